// Round 10
// baseline (1866.744 us; speedup 1.0000x reference)
//
#include <hip/hip_runtime.h>
#include <math.h>

// ---------------- constants ----------------
#define B_    16
#define N_    2048
#define INDIM 64
#define DIM_  512
#define HEADS 8
#define DEPTH 4
#define KLIN  256
#define NCLS  2
#define DH    64
#define EPSF  1e-5f

typedef __attribute__((ext_vector_type(8))) short short8v;
typedef __attribute__((ext_vector_type(4))) short short4v;
typedef __attribute__((ext_vector_type(4))) float f32x4;

#define SBAR() __builtin_amdgcn_sched_barrier(0)

// fp32 -> bf16 round-to-nearest-even (finite inputs)
__device__ __forceinline__ short f2bf(float f) {
  unsigned u = __float_as_uint(f);
  u += 0x7FFFu + ((u >> 16) & 1u);
  return (short)(u >> 16);
}

__device__ __forceinline__ float wave_sum(float v) {
  #pragma unroll
  for (int o = 32; o > 0; o >>= 1) v += __shfl_xor(v, o);
  return v;
}

// tanh-GELU via sigmoid identity (~7 VALU vs ~45+ libm tanhf)
__device__ __forceinline__ float gelu_tanh(float x) {
  float u = x * (1.5957691216057308f + 0.07135481627f * x * x);
  return x / (1.f + __expf(-u));
}

// async global->LDS, 16B per lane; LDS dest = wave-uniform base + lane*16
__device__ __forceinline__ void gl_lds16(const short* g, short* l) {
  __builtin_amdgcn_global_load_lds(
      (const __attribute__((address_space(1))) unsigned int*)g,
      (__attribute__((address_space(3))) unsigned int*)l, 16, 0, 0);
}

// ---------------- converts (once per launch) ----------------
__global__ __launch_bounds__(256) void tconv_k(const float* __restrict__ src,
                                               short* __restrict__ dst, int R,
                                               int C, long long sSrc,
                                               long long sDst) {
  __shared__ float tile[32][33];
  int c0 = blockIdx.x * 32, r0 = blockIdx.y * 32;
  src += (long long)blockIdx.z * sSrc;
  dst += (long long)blockIdx.z * sDst;
  int tx = threadIdx.x & 31, ty = threadIdx.x >> 5;
  #pragma unroll
  for (int rr = 0; rr < 4; ++rr)
    tile[ty + rr * 8][tx] = src[(long long)(r0 + ty + rr * 8) * C + c0 + tx];
  __syncthreads();
  #pragma unroll
  for (int rr = 0; rr < 4; ++rr) {
    int c = ty + rr * 8;
    dst[(long long)(c0 + c) * R + r0 + tx] = f2bf(tile[tx][c]);
  }
}

__global__ __launch_bounds__(256) void cconv_k(const float* __restrict__ src,
                                               short* __restrict__ dst,
                                               int n8) {
  int i = blockIdx.x * 256 + threadIdx.x;
  if (i < n8) {
    const float* s = src + (long long)i * 8;
    float4 a = *(const float4*)s, c = *(const float4*)(s + 4);
    short8v o = {f2bf(a.x), f2bf(a.y), f2bf(a.z), f2bf(a.w),
                 f2bf(c.x), f2bf(c.y), f2bf(c.z), f2bf(c.w)};
    *(short8v*)(dst + (long long)i * 8) = o;
  }
}

// ---------------- bf16 tile transpose: [R][C] -> [C][R], batched ----------
__global__ __launch_bounds__(256) void tpose_k(const short* __restrict__ src,
                                               short* __restrict__ dst, int R,
                                               int C, long long sSrc,
                                               long long sDst) {
  __shared__ __align__(16) short tile[64][72];
  int c0 = blockIdx.x * 64, r0 = blockIdx.y * 64;
  src += (long long)blockIdx.z * sSrc;
  dst += (long long)blockIdx.z * sDst;
  int t = threadIdx.x;
  #pragma unroll
  for (int rep = 0; rep < 2; ++rep) {
    int row = rep * 32 + (t >> 3), c8 = (t & 7) * 8;
    *(short8v*)&tile[row][c8] =
        *(const short8v*)(src + (long long)(r0 + row) * C + c0 + c8);
  }
  __syncthreads();
  #pragma unroll
  for (int rep = 0; rep < 2; ++rep) {
    int c = rep * 32 + (t >> 3), r8 = (t & 7) * 8;
    short8v o;
    #pragma unroll
    for (int j = 0; j < 8; ++j) o[j] = tile[r8 + j][c];
    *(short8v*)(dst + (long long)(c0 + c) * R + r0 + r8) = o;
  }
}

// ---------------- LayerNorm: fp32 in, bf16 out ----------------
__global__ __launch_bounds__(256) void ln_k(const float* __restrict__ h,
                                            const float* __restrict__ s,
                                            const float* __restrict__ b,
                                            short* __restrict__ z) {
  int lane = threadIdx.x & 63;
  long long row = ((long long)blockIdx.x << 2) + (threadIdx.x >> 6);
  const float* hr = h + row * DIM_ + lane * 8;
  float4 a = *(const float4*)hr;
  float4 c = *(const float4*)(hr + 4);
  float sum = a.x + a.y + a.z + a.w + c.x + c.y + c.z + c.w;
  sum = wave_sum(sum);
  float mu = sum * (1.f / DIM_);
  float d[8] = {a.x - mu, a.y - mu, a.z - mu, a.w - mu,
                c.x - mu, c.y - mu, c.z - mu, c.w - mu};
  float vs = 0.f;
  #pragma unroll
  for (int i = 0; i < 8; ++i) vs += d[i] * d[i];
  vs = wave_sum(vs);
  float rstd = rsqrtf(vs * (1.f / DIM_) + EPSF);
  const float* sp = s + lane * 8;
  const float* bp = b + lane * 8;
  float4 s0 = *(const float4*)sp, s1 = *(const float4*)(sp + 4);
  float4 b0 = *(const float4*)bp, b1 = *(const float4*)(bp + 4);
  float o[8];
  o[0] = d[0] * rstd * s0.x + b0.x; o[1] = d[1] * rstd * s0.y + b0.y;
  o[2] = d[2] * rstd * s0.z + b0.z; o[3] = d[3] * rstd * s0.w + b0.w;
  o[4] = d[4] * rstd * s1.x + b1.x; o[5] = d[5] * rstd * s1.y + b1.y;
  o[6] = d[6] * rstd * s1.z + b1.z; o[7] = d[7] * rstd * s1.w + b1.w;
  short8v ov = {f2bf(o[0]), f2bf(o[1]), f2bf(o[2]), f2bf(o[3]),
                f2bf(o[4]), f2bf(o[5]), f2bf(o[6]), f2bf(o[7])};
  *(short8v*)(z + row * DIM_ + lane * 8) = ov;
}

// ---------------- bf16 MFMA GEMM, 2-phase pipeline (small shapes) --------
// epi: 0 none; 1 +bias; 2 +bias+resid[(m%resMod)*ldc+n] (fp32); 3 gelu(+bias)
template <int OUTBF, int BM, int BN>
__global__ __launch_bounds__(256) void gemm_bf(
    const short* __restrict__ A, const short* __restrict__ Bsrc,
    const float* __restrict__ bias, const float* __restrict__ resid,
    void* __restrict__ Cv, int M, int N, int K, int lda, int ldb, int ldc,
    long long sAb, long long sBb, long long sCb, int dualThresh,
    long long dualOff, int epi, int resMod) {
  constexpr int MT = BM / 32;   // frag rows per wave
  constexpr int NT = BN / 32;   // frag cols per wave
  constexpr int NLD = BM / 32 + BN / 32;  // global_load_lds per thread / tile
  int zz = blockIdx.z;
  A += (long long)zz * sAb;
  Bsrc += (long long)zz * sBb;
  int bm = blockIdx.y * BM, bn = blockIdx.x * BN;
  if (dualThresh && bm >= dualThresh) Bsrc += dualOff;
  int t = threadIdx.x;
  __shared__ __align__(16) short Alds[2][BM * 64];
  __shared__ __align__(16) short Blds[2][BN * 64];
  int lane = t & 63, wid = t >> 6;
  int lr = lane & 15, q = lane >> 4;
  int wm = (wid >> 1) * (BM / 2), wn = (wid & 1) * (BN / 2);
  int rl = lane >> 3;          // row within 8-row group
  int cs = (lane & 7) ^ rl;    // swizzled source chunk
  f32x4 acc[MT][NT] = {};

  // stage one BK=64 tile (A + B) into LDS buffer `buf`
  auto stage = [&](int buf, int k0) {
    #pragma unroll
    for (int i = 0; i < BM / 32; ++i) {
      int rb = i * 32 + wid * 8;
      gl_lds16(A + (long long)(bm + rb + rl) * lda + k0 + cs * 8,
               &Alds[buf][rb * 64]);
    }
    #pragma unroll
    for (int i = 0; i < BN / 32; ++i) {
      int rb = i * 32 + wid * 8;
      gl_lds16(Bsrc + (long long)(bn + rb + rl) * ldb + k0 + cs * 8,
               &Blds[buf][rb * 64]);
    }
  };

  stage(0, 0);  // prologue: tile 0 in flight
  int cur = 0;
  for (int k0 = 0; k0 < K; k0 += 64, cur ^= 1) {
    if (k0 + 64 < K) {
      stage(cur ^ 1, k0 + 64);  // prefetch next tile (overlaps MFMA below)
      SBAR();  // pin issue above the counted wait
      asm volatile("s_waitcnt vmcnt(%0)" ::"n"(NLD) : "memory");  // tile k0 done
    } else {
      SBAR();
      asm volatile("s_waitcnt vmcnt(0)" ::: "memory");
    }
    __builtin_amdgcn_s_barrier();        // everyone's tile-k0 loads landed
    SBAR();                              // keep ds_reads below the barrier
    #pragma unroll
    for (int kk2 = 0; kk2 < 2; ++kk2) {
      short8v af[MT], bfr[NT];
      #pragma unroll
      for (int mi = 0; mi < MT; ++mi)
        af[mi] = *(const short8v*)&Alds[cur][(wm + mi * 16 + lr) * 64 +
                                             (((kk2 << 2) | q) ^ (lr & 7)) * 8];
      #pragma unroll
      for (int ni = 0; ni < NT; ++ni)
        bfr[ni] = *(const short8v*)&Blds[cur][(wn + ni * 16 + lr) * 64 +
                                              (((kk2 << 2) | q) ^ (lr & 7)) * 8];
      #pragma unroll
      for (int mi = 0; mi < MT; ++mi)
        #pragma unroll
        for (int ni = 0; ni < NT; ++ni)
          acc[mi][ni] = __builtin_amdgcn_mfma_f32_16x16x32_bf16(
              bfr[ni], af[mi], acc[mi][ni], 0, 0, 0);  // swapped: cols in regs
    }
    SBAR();                              // reads of buf[cur] complete here
    __builtin_amdgcn_s_barrier();        // before next iter overwrites it
  }

  #pragma unroll
  for (int mi = 0; mi < MT; ++mi) {
    int m = bm + wm + mi * 16 + lr;
    int rm = (epi == 2 && resMod) ? (m % resMod) : m;
    #pragma unroll
    for (int ni = 0; ni < NT; ++ni) {
      int nb = bn + wn + ni * 16 + q * 4;
      f32x4 v = acc[mi][ni];
      if (epi >= 1) {
        float4 bb = *(const float4*)(bias + nb);
        v[0] += bb.x; v[1] += bb.y; v[2] += bb.z; v[3] += bb.w;
      }
      if (epi == 2) {
        float4 rr = *(const float4*)(resid + (long long)rm * ldc + nb);
        v[0] += rr.x; v[1] += rr.y; v[2] += rr.z; v[3] += rr.w;
      } else if (epi == 3) {
        v[0] = gelu_tanh(v[0]); v[1] = gelu_tanh(v[1]);
        v[2] = gelu_tanh(v[2]); v[3] = gelu_tanh(v[3]);
      }
      long long base = (long long)zz * sCb + (long long)m * ldc + nb;
      if (OUTBF) {
        short4v o = {f2bf(v[0]), f2bf(v[1]), f2bf(v[2]), f2bf(v[3])};
        *(short4v*)((short*)Cv + base) = o;
      } else {
        *(float4*)((float*)Cv + base) = make_float4(v[0], v[1], v[2], v[3]);
      }
    }
  }
}

// ---------------- 8-phase bf16 MFMA GEMM (big shapes, batched) ------------
// BMxBN tile, BK=64, 512 threads = 8 waves (2M x 4N); per-wave tile
// (BM/2) x (BN/4). 4 compute phases per K-tile (quadrants). Counted
// vmcnt(LA) per K-tile, half-tile staging ring. R8 (best timed config):
// B-lo+B-hi(t+1) issued at P3 — issue-to-wait distance 1.5 phases. T1:
// bijective XCD swizzle per z-slice. Batched via blockIdx.z strides;
// dual-B row split. lda=ldb=K; ldc=N. EPI: 0 none; 2 bias+resid; 3 gelu.
template <int OUTBF, int BM, int BN, int EPI>
__global__ __launch_bounds__(512, 2) void gemm8(
    const short* __restrict__ A, const short* __restrict__ Bt,
    const float* __restrict__ bias, const float* __restrict__ resid,
    void* __restrict__ Cv, int M, int N, int K, long long sAb, long long sBb,
    long long sCb, int dualThresh, long long dualOff) {
  constexpr int MH = BM / 64;     // 16-row frags per row-half per wave: 4 or 2
  constexpr int WCOL = BN / 4;    // cols per wave (64 or 32)
  constexpr int NT = WCOL / 16;   // 4 or 2
  constexpr int NTH = NT / 2;     // col-half frags: 2 or 1
  constexpr int LB = BN / 128;    // gl_lds per B-half: 2 or 1
  constexpr int LA = BM / 128;    // gl_lds per A-half: 2 or 1
  __shared__ __align__(16) short Alds[2][BM * 64];
  __shared__ __align__(16) short Blds[2][BN * 64];
  const int tid = threadIdx.x;
  const int lane = tid & 63, wid = tid >> 6;
  const int lr = lane & 15, q = lane >> 4;
  const int wm = (wid >> 2) * (BM / 2), wn = (wid & 3) * WCOL;
  const int rl = lane >> 3, cs = (lane & 7) ^ rl;
  const int zz = blockIdx.z;
  A += (long long)zz * sAb;
  Bt += (long long)zz * sBb;
  const int nwg = gridDim.x * gridDim.y;
  int bid = blockIdx.y * gridDim.x + blockIdx.x;
  const int nx8 = nwg >> 3, r8 = nwg & 7, xcd = bid & 7, loc = bid >> 3;
  int swz = (xcd < r8 ? xcd * (nx8 + 1) : r8 * (nx8 + 1) + (xcd - r8) * nx8)
            + loc;
  const int bm = (swz / gridDim.x) * BM, bn = (swz % gridDim.x) * BN;
  if (dualThresh && bm >= dualThresh) Bt += dualOff;
  const short* Ag = A + (long long)bm * K + cs * 8;
  const short* Bg = Bt + (long long)bn * K + cs * 8;
  f32x4 acc[2 * MH][NT] = {};

  auto stageA = [&](int slot, int h, int k0) {
    #pragma unroll
    for (int j = 0; j < LA; ++j) {
      int rb = h * (BM / 2) + j * 64 + wid * 8;
      gl_lds16(Ag + (long long)(rb + rl) * K + k0, &Alds[slot][rb * 64]);
    }
  };
  auto stageB = [&](int slot, int h, int k0) {
    #pragma unroll
    for (int j = 0; j < LB; ++j) {
      int rb = h * (BN / 2) + j * 64 + wid * 8;
      gl_lds16(Bg + (long long)(rb + rl) * K + k0, &Blds[slot][rb * 64]);
    }
  };
  auto rd = [&](const short* Ls, int row, int kk) -> short8v {
    return *(const short8v*)&Ls[row * 64 + ((((kk << 2) | q) ^ (lr & 7)) << 3)];
  };
  auto mfma4 = [&](short8v (&af)[MH][2], short8v (&bf)[NTH][2], int mo,
                   int no) {
    #pragma unroll
    for (int mi = 0; mi < MH; ++mi)
      #pragma unroll
      for (int ni = 0; ni < NTH; ++ni)
        #pragma unroll
        for (int kk = 0; kk < 2; ++kk)
          acc[mo + mi][no + ni] = __builtin_amdgcn_mfma_f32_16x16x32_bf16(
              bf[ni][kk], af[mi][kk], acc[mo + mi][no + ni], 0, 0, 0);
  };

  const int T = K >> 6;
  stageA(0, 0, 0); stageA(0, 1, 0); stageB(0, 0, 0); stageB(0, 1, 0);
  if (T > 1) {
    stageA(1, 0, 64);
    SBAR();
    asm volatile("s_waitcnt vmcnt(%0)" ::"n"(LA) : "memory");
  } else {
    SBAR();
    asm volatile("s_waitcnt vmcnt(0)" ::: "memory");
  }
  __builtin_amdgcn_s_barrier();

  for (int tt = 0; tt < T; ++tt) {
    const int s = tt & 1, ns = s ^ 1;
    const int kn = (tt + 1) << 6, kn2 = (tt + 2) << 6;
    const short* Als = Alds[s];
    const short* Bls = Blds[s];
    short8v af0[MH][2], af1[MH][2], bf0[NTH][2], bf1[NTH][2];
    // ---- P1: quadrant (row-lo x col-lo); stage A-hi(t+1) ----
    SBAR();
    #pragma unroll
    for (int mi = 0; mi < MH; ++mi)
      #pragma unroll
      for (int kk = 0; kk < 2; ++kk)
        af0[mi][kk] = rd(Als, wm + mi * 16 + lr, kk);
    #pragma unroll
    for (int ni = 0; ni < NTH; ++ni)
      #pragma unroll
      for (int kk = 0; kk < 2; ++kk)
        bf0[ni][kk] = rd(Bls, wn + ni * 16 + lr, kk);
    if (tt + 1 < T) stageA(ns, 1, kn);
    if (BN == 256) asm volatile("s_waitcnt lgkmcnt(8)" ::: "memory");
    SBAR();
    __builtin_amdgcn_s_barrier();
    asm volatile("s_waitcnt lgkmcnt(0)" ::: "memory");
    SBAR();
    __builtin_amdgcn_s_setprio(1);
    mfma4(af0, bf0, 0, 0);
    __builtin_amdgcn_s_setprio(0);
    SBAR();
    __builtin_amdgcn_s_barrier();
    // ---- P2: (row-lo x col-hi) ----
    SBAR();
    #pragma unroll
    for (int ni = 0; ni < NTH; ++ni)
      #pragma unroll
      for (int kk = 0; kk < 2; ++kk)
        bf1[ni][kk] = rd(Bls, wn + (NTH + ni) * 16 + lr, kk);
    SBAR();
    __builtin_amdgcn_s_barrier();
    asm volatile("s_waitcnt lgkmcnt(0)" ::: "memory");
    SBAR();
    __builtin_amdgcn_s_setprio(1);
    mfma4(af0, bf1, 0, NTH);
    __builtin_amdgcn_s_setprio(0);
    SBAR();
    __builtin_amdgcn_s_barrier();
    // ---- P3: (row-hi x col-lo); stage B-lo(t+1) + B-hi(t+1) ----
    SBAR();
    #pragma unroll
    for (int mi = 0; mi < MH; ++mi)
      #pragma unroll
      for (int kk = 0; kk < 2; ++kk)
        af1[mi][kk] = rd(Als, wm + MH * 16 + mi * 16 + lr, kk);
    if (tt + 1 < T) { stageB(ns, 0, kn); stageB(ns, 1, kn); }
    SBAR();
    __builtin_amdgcn_s_barrier();
    asm volatile("s_waitcnt lgkmcnt(0)" ::: "memory");
    SBAR();
    __builtin_amdgcn_s_setprio(1);
    mfma4(af1, bf0, MH, 0);
    __builtin_amdgcn_s_setprio(0);
    SBAR();
    __builtin_amdgcn_s_barrier();
    // ---- P4: (row-hi x col-hi); stage A-lo(t+2); counted wait ----
    SBAR();
    if (tt + 2 < T) stageA(s, 0, kn2);
    SBAR();
    __builtin_amdgcn_s_barrier();
    __builtin_amdgcn_s_setprio(1);
    mfma4(af1, bf1, MH, NTH);
    __builtin_amdgcn_s_setprio(0);
    if (tt + 2 < T) {
      SBAR();
      asm volatile("s_waitcnt vmcnt(%0)" ::"n"(LA) : "memory");  // t+1 landed
    } else if (tt + 1 < T) {
      SBAR();
      asm volatile("s_waitcnt vmcnt(0)" ::: "memory");  // final tile landed
    }
    SBAR();
    __builtin_amdgcn_s_barrier();
  }

  #pragma unroll
  for (int mi = 0; mi < 2 * MH; ++mi) {
    int m = bm + wm + mi * 16 + lr;
    #pragma unroll
    for (int nj = 0; nj < NT; ++nj) {
      int nb = bn + wn + nj * 16 + q * 4;
      f32x4 v = acc[mi][nj];
      if (EPI >= 1) {
        float4 bb = *(const float4*)(bias + nb);
        v[0] += bb.x; v[1] += bb.y; v[2] += bb.z; v[3] += bb.w;
      }
      if (EPI == 2) {
        float4 rr = *(const float4*)(resid + (long long)m * N + nb);
        v[0] += rr.x; v[1] += rr.y; v[2] += rr.z; v[3] += rr.w;
      } else if (EPI == 3) {
        v[0] = gelu_tanh(v[0]); v[1] = gelu_tanh(v[1]);
        v[2] = gelu_tanh(v[2]); v[3] = gelu_tanh(v[3]);
      }
      long long base = (long long)zz * sCb + (long long)m * N + nb;
      if (OUTBF) {
        short4v o = {f2bf(v[0]), f2bf(v[1]), f2bf(v[2]), f2bf(v[3])};
        *(short4v*)((short*)Cv + base) = o;
      } else {
        *(float4*)((float*)Cv + base) = make_float4(v[0], v[1], v[2], v[3]);
      }
    }
  }
}

// ---------------- merged 2-phase variant of gemm8 (for small tiles) -------
// Same staging ring and vmcnt values as gemm8; 4 compute quadrants merged
// into 2 row-half phases. R10 = R8 config (best timed, 1810us): ALL of tile
// t+1 (A-hi, B-lo, B-hi) issued in P1; A-lo(t+2) in P2; end-of-tile
// vmcnt(LA) allows only A-lo(t+2) outstanding. The R9 "split staging"
// variant timed WORSE end-to-end (1836) despite better per-dispatch replay
// numbers — replay-pass readings are not commensurable for this kernel.
// Per-acc K-order identical -> bit-identical C.
template <int OUTBF, int BM, int BN, int EPI>
__global__ __launch_bounds__(512, 2) void gemm8m(
    const short* __restrict__ A, const short* __restrict__ Bt,
    const float* __restrict__ bias, const float* __restrict__ resid,
    void* __restrict__ Cv, int M, int N, int K, long long sAb, long long sBb,
    long long sCb, int dualThresh, long long dualOff) {
  constexpr int MH = BM / 64;
  constexpr int WCOL = BN / 4;
  constexpr int NT = WCOL / 16;
  constexpr int NTH = NT / 2;
  constexpr int LB = BN / 128;
  constexpr int LA = BM / 128;
  __shared__ __align__(16) short Alds[2][BM * 64];
  __shared__ __align__(16) short Blds[2][BN * 64];
  const int tid = threadIdx.x;
  const int lane = tid & 63, wid = tid >> 6;
  const int lr = lane & 15, q = lane >> 4;
  const int wm = (wid >> 2) * (BM / 2), wn = (wid & 3) * WCOL;
  const int rl = lane >> 3, cs = (lane & 7) ^ rl;
  const int zz = blockIdx.z;
  A += (long long)zz * sAb;
  Bt += (long long)zz * sBb;
  const int nwg = gridDim.x * gridDim.y;
  int bid = blockIdx.y * gridDim.x + blockIdx.x;
  const int nx8 = nwg >> 3, r8 = nwg & 7, xcd = bid & 7, loc = bid >> 3;
  int swz = (xcd < r8 ? xcd * (nx8 + 1) : r8 * (nx8 + 1) + (xcd - r8) * nx8)
            + loc;
  const int bm = (swz / gridDim.x) * BM, bn = (swz % gridDim.x) * BN;
  if (dualThresh && bm >= dualThresh) Bt += dualOff;
  const short* Ag = A + (long long)bm * K + cs * 8;
  const short* Bg = Bt + (long long)bn * K + cs * 8;
  f32x4 acc[2 * MH][NT] = {};

  auto stageA = [&](int slot, int h, int k0) {
    #pragma unroll
    for (int j = 0; j < LA; ++j) {
      int rb = h * (BM / 2) + j * 64 + wid * 8;
      gl_lds16(Ag + (long long)(rb + rl) * K + k0, &Alds[slot][rb * 64]);
    }
  };
  auto stageB = [&](int slot, int h, int k0) {
    #pragma unroll
    for (int j = 0; j < LB; ++j) {
      int rb = h * (BN / 2) + j * 64 + wid * 8;
      gl_lds16(Bg + (long long)(rb + rl) * K + k0, &Blds[slot][rb * 64]);
    }
  };
  auto rd = [&](const short* Ls, int row, int kk) -> short8v {
    return *(const short8v*)&Ls[row * 64 + ((((kk << 2) | q) ^ (lr & 7)) << 3)];
  };
  auto mfma4 = [&](short8v (&af)[MH][2], short8v (&bf)[NTH][2], int mo,
                   int no) {
    #pragma unroll
    for (int mi = 0; mi < MH; ++mi)
      #pragma unroll
      for (int ni = 0; ni < NTH; ++ni)
        #pragma unroll
        for (int kk = 0; kk < 2; ++kk)
          acc[mo + mi][no + ni] = __builtin_amdgcn_mfma_f32_16x16x32_bf16(
              bf[ni][kk], af[mi][kk], acc[mo + mi][no + ni], 0, 0, 0);
  };

  const int T = K >> 6;
  stageA(0, 0, 0); stageA(0, 1, 0); stageB(0, 0, 0); stageB(0, 1, 0);
  if (T > 1) {
    stageA(1, 0, 64);
    SBAR();
    asm volatile("s_waitcnt vmcnt(%0)" ::"n"(LA) : "memory");
  } else {
    SBAR();
    asm volatile("s_waitcnt vmcnt(0)" ::: "memory");
  }
  __builtin_amdgcn_s_barrier();

  for (int tt = 0; tt < T; ++tt) {
    const int s = tt & 1, ns = s ^ 1;
    const int kn = (tt + 1) << 6, kn2 = (tt + 2) << 6;
    const short* Als = Alds[s];
    const short* Bls = Blds[s];
    short8v af0[MH][2], af1[MH][2], bf0[NTH][2], bf1[NTH][2];
    // ---- P1 (merged): row-lo x all cols; stage ALL of tile t+1 ----
    SBAR();
    #pragma unroll
    for (int mi = 0; mi < MH; ++mi)
      #pragma unroll
      for (int kk = 0; kk < 2; ++kk)
        af0[mi][kk] = rd(Als, wm + mi * 16 + lr, kk);
    #pragma unroll
    for (int ni = 0; ni < NTH; ++ni)
      #pragma unroll
      for (int kk = 0; kk < 2; ++kk) {
        bf0[ni][kk] = rd(Bls, wn + ni * 16 + lr, kk);
        bf1[ni][kk] = rd(Bls, wn + (NTH + ni) * 16 + lr, kk);
      }
    if (tt + 1 < T) {
      stageA(ns, 1, kn);
      stageB(ns, 0, kn);
      stageB(ns, 1, kn);
    }
    SBAR();
    __builtin_amdgcn_s_barrier();
    asm volatile("s_waitcnt lgkmcnt(0)" ::: "memory");
    SBAR();
    __builtin_amdgcn_s_setprio(1);
    mfma4(af0, bf0, 0, 0);
    mfma4(af0, bf1, 0, NTH);
    __builtin_amdgcn_s_setprio(0);
    SBAR();
    __builtin_amdgcn_s_barrier();
    // ---- P2 (merged): row-hi x all cols; stage A-lo(t+2) ----
    SBAR();
    #pragma unroll
    for (int mi = 0; mi < MH; ++mi)
      #pragma unroll
      for (int kk = 0; kk < 2; ++kk)
        af1[mi][kk] = rd(Als, wm + MH * 16 + mi * 16 + lr, kk);
    if (tt + 2 < T) stageA(s, 0, kn2);
    SBAR();
    __builtin_amdgcn_s_barrier();
    asm volatile("s_waitcnt lgkmcnt(0)" ::: "memory");
    SBAR();
    __builtin_amdgcn_s_setprio(1);
    mfma4(af1, bf0, MH, 0);
    mfma4(af1, bf1, MH, NTH);
    __builtin_amdgcn_s_setprio(0);
    if (tt + 2 < T) {
      SBAR();
      asm volatile("s_waitcnt vmcnt(%0)" ::"n"(LA) : "memory");  // t+1 landed
    } else if (tt + 1 < T) {
      SBAR();
      asm volatile("s_waitcnt vmcnt(0)" ::: "memory");
    }
    SBAR();
    __builtin_amdgcn_s_barrier();
  }

  #pragma unroll
  for (int mi = 0; mi < 2 * MH; ++mi) {
    int m = bm + wm + mi * 16 + lr;
    #pragma unroll
    for (int nj = 0; nj < NT; ++nj) {
      int nb = bn + wn + nj * 16 + q * 4;
      f32x4 v = acc[mi][nj];
      if (EPI >= 1) {
        float4 bb = *(const float4*)(bias + nb);
        v[0] += bb.x; v[1] += bb.y; v[2] += bb.z; v[3] += bb.w;
      }
      if (EPI == 2) {
        float4 rr = *(const float4*)(resid + (long long)m * N + nb);
        v[0] += rr.x; v[1] += rr.y; v[2] += rr.z; v[3] += rr.w;
      } else if (EPI == 3) {
        v[0] = gelu_tanh(v[0]); v[1] = gelu_tanh(v[1]);
        v[2] = gelu_tanh(v[2]); v[3] = gelu_tanh(v[3]);
      }
      long long base = (long long)zz * sCb + (long long)m * N + nb;
      if (OUTBF) {
        short4v o = {f2bf(v[0]), f2bf(v[1]), f2bf(v[2]), f2bf(v[3])};
        *(short4v*)((short*)Cv + base) = o;
      } else {
        *(float4*)((float*)Cv + base) = make_float4(v[0], v[1], v[2], v[3]);
      }
    }
  }
}

// ---------------- fused Linformer attention, bf16 MFMA ----------------
// QBLK=64, 256 threads, LDS 78KB -> 2 blocks/CU (proven R3 config).
// QK^T operand-swapped: sacc[nt][r] = S[q=16w+lr][k=nt*16+qd*4+r]; softmax
// reduce = 2 shfl; P-writes packed short4 (2-way banking, free).
// V pre-transposed globally -> conflict-free row staging.
__global__ __launch_bounds__(256) void attn_k(short* __restrict__ qc,
                                              const short* __restrict__ kvp,
                                              const short* __restrict__ vt,
                                              float scale) {
  int n0 = blockIdx.x * 64, hh = blockIdx.y, b = blockIdx.z;
  int t = threadIdx.x;
  int lane = t & 63, w = t >> 6;
  int lr = lane & 15, qd = lane >> 4;

  __shared__ __align__(16) short Qlds[64][72];
  __shared__ __align__(16) short Kbuf[256 * 72];  // K, then aliased as P
  __shared__ __align__(16) short Vt[64][264];
  auto Klds = (short(*)[72])Kbuf;
  auto Plds = (short(*)[264])Kbuf;

  short* qptr = qc + (long long)b * N_ * DIM_ + hh * DH;
  const short* kptr = kvp + (long long)b * 2 * KLIN * DIM_ + hh * DH;
  const short* vtp = vt + (long long)b * DIM_ * KLIN + (long long)hh * DH * KLIN;

  #pragma unroll
  for (int rep = 0; rep < 2; ++rep) {
    int L = rep * 256 + t, row = L >> 3, c8 = (L & 7) << 3;
    *(short8v*)&Qlds[row][c8] =
        *(const short8v*)(qptr + (long long)(n0 + row) * DIM_ + c8);
  }
  #pragma unroll
  for (int rep = 0; rep < 8; ++rep) {
    int L = rep * 256 + t, row = L >> 3, c8 = (L & 7) << 3;
    *(short8v*)&Klds[row][c8] =
        *(const short8v*)(kptr + (long long)row * DIM_ + c8);
  }
  // V^T rows (dh-major, 256 k-cols each): coalesced, conflict-free staging
  #pragma unroll
  for (int rep = 0; rep < 8; ++rep) {
    int L = rep * 256 + t, row = L >> 5, c8 = (L & 31) << 3;
    *(short8v*)&Vt[row][c8] =
        *(const short8v*)(vtp + (long long)row * KLIN + c8);
  }
  __syncthreads();

  short8v qa0 = *(const short8v*)&Qlds[16 * w + lr][qd * 8];
  short8v qa1 = *(const short8v*)&Qlds[16 * w + lr][32 + qd * 8];
  f32x4 sacc[16];
  #pragma unroll
  for (int nt = 0; nt < 16; ++nt) {
    short8v b0 = *(const short8v*)&Klds[nt * 16 + lr][qd * 8];
    short8v b1 = *(const short8v*)&Klds[nt * 16 + lr][32 + qd * 8];
    f32x4 acc = {};
    acc = __builtin_amdgcn_mfma_f32_16x16x32_bf16(b0, qa0, acc, 0, 0, 0);
    acc = __builtin_amdgcn_mfma_f32_16x16x32_bf16(b1, qa1, acc, 0, 0, 0);
    sacc[nt] = acc;
  }

  // softmax over the lane-local row slice (64 vals) + 2-shfl qd reduction.
  // scale folds into the exp argument: softmax(s*S) = exp(scale*(S - maxS)).
  float mx = -1e30f;
  #pragma unroll
  for (int nt = 0; nt < 16; ++nt)
    #pragma unroll
    for (int r = 0; r < 4; ++r) mx = fmaxf(mx, sacc[nt][r]);
  mx = fmaxf(mx, __shfl_xor(mx, 16));
  mx = fmaxf(mx, __shfl_xor(mx, 32));
  float rs = 0.f;
  #pragma unroll
  for (int nt = 0; nt < 16; ++nt)
    #pragma unroll
    for (int r = 0; r < 4; ++r) {
      float e = __expf((sacc[nt][r] - mx) * scale);
      sacc[nt][r] = e;
      rs += e;
    }
  rs += __shfl_xor(rs, 16);
  rs += __shfl_xor(rs, 32);
  float inv = 1.f / rs;

  __syncthreads();  // Klds reads done; reuse as Plds
  #pragma unroll
  for (int nt = 0; nt < 16; ++nt) {
    short4v p = {f2bf(sacc[nt][0] * inv), f2bf(sacc[nt][1] * inv),
                 f2bf(sacc[nt][2] * inv), f2bf(sacc[nt][3] * inv)};
    *(short4v*)&Plds[16 * w + lr][nt * 16 + qd * 4] = p;
  }
  __syncthreads();

  f32x4 out[4] = {};
  #pragma unroll
  for (int k0 = 0; k0 < 8; ++k0) {
    short8v ap = *(const short8v*)&Plds[16 * w + lr][k0 * 32 + qd * 8];
    #pragma unroll
    for (int n2 = 0; n2 < 4; ++n2) {
      short8v bv = *(const short8v*)&Vt[n2 * 16 + lr][k0 * 32 + qd * 8];
      out[n2] =
          __builtin_amdgcn_mfma_f32_16x16x32_bf16(bv, ap, out[n2], 0, 0, 0);
    }
  }

  long long rowoff = (long long)(n0 + 16 * w + lr) * DIM_;
  #pragma unroll
  for (int n2 = 0; n2 < 4; ++n2) {
    short4v o = {f2bf(out[n2][0]), f2bf(out[n2][1]), f2bf(out[n2][2]),
                 f2bf(out[n2][3])};
    *(short4v*)(qptr + rowoff + n2 * 16 + qd * 4) = o;
  }
}

// ---------------- two-stage mean pool ----------------
__global__ __launch_bounds__(256) void pool1_k(const float* __restrict__ h,
                                               float* __restrict__ partial) {
  int stripe = blockIdx.x, b = blockIdx.y;
  int c4 = (threadIdx.x & 127) * 4, half = threadIdx.x >> 7;
  const float* base =
      h + ((long long)b * N_ + stripe * 128 + half * 64) * DIM_ + c4;
  float4 acc = {0.f, 0.f, 0.f, 0.f};
  for (int r = 0; r < 64; ++r) {
    float4 v = *(const float4*)(base + (long long)r * DIM_);
    acc.x += v.x; acc.y += v.y; acc.z += v.z; acc.w += v.w;
  }
  __shared__ float red[512];
  if (half == 1) *(float4*)&red[c4] = acc;
  __syncthreads();
  if (half == 0) {
    float4 o = *(const float4*)&red[c4];
    o.x += acc.x; o.y += acc.y; o.z += acc.z; o.w += acc.w;
    *(float4*)&partial[((long long)b * 16 + stripe) * DIM_ + c4] = o;
  }
}
__global__ __launch_bounds__(256) void pool2_k(const float* __restrict__ partial,
                                               float* __restrict__ pooled) {
  int b = blockIdx.x;
  for (int c = threadIdx.x; c < DIM_; c += 256) {
    float s = 0.f;
    for (int k = 0; k < 16; ++k) s += partial[((long long)b * 16 + k) * DIM_ + c];
    pooled[b * DIM_ + c] = s * (1.f / N_);
  }
}

// ---------------- final FC [16,512]@[512,2] ----------------
__global__ __launch_bounds__(64) void fc_k(const float* __restrict__ pooled,
                                           const float* __restrict__ fc_w,
                                           const float* __restrict__ fc_b,
                                           float* __restrict__ out) {
  int t = threadIdx.x;
  if (t < B_ * NCLS) {
    int b = t >> 1, c = t & 1;
    float s = fc_b[c];
    for (int d = 0; d < DIM_; ++d)
      s += pooled[b * DIM_ + d] * fc_w[d * NCLS + c];
    out[t] = s;
  }
}

extern "C" void kernel_launch(void* const* d_in, const int* in_sizes, int n_in,
                              void* d_out, int out_size, void* d_ws,
                              size_t ws_size, hipStream_t stream) {
  const float* x     = (const float*)d_in[0];
  const float* emb_w = (const float*)d_in[1];
  const float* emb_b = (const float*)d_in[2];
  const float* pos   = (const float*)d_in[3];
  const float* ln1_s = (const float*)d_in[4];
  const float* ln1_b = (const float*)d_in[5];
  const float* wq    = (const float*)d_in[6];
  const float* wk    = (const float*)d_in[7];
  const float* wv    = (const float*)d_in[8];
  const float* pk    = (const float*)d_in[9];
  const float* pv    = (const float*)d_in[10];
  const float* wo    = (const float*)d_in[11];
  const float* wo_b  = (const float*)d_in[12];
  const float* ln2_s = (const float*)d_in[13];
  const float* ln2_b = (const float*)d_in[14];
  const float* w1    = (const float*)d_in[15];
  const float* b1    = (const float*)d_in[16];
  const float* w2    = (const float*)d_in[17];
  const float* b2    = (const float*)d_in[18];
  const float* fc_w  = (const float*)d_in[19];
  const float* fc_b  = (const float*)d_in[20];
  float* out = (float*)d_out;

  // ---- adaptive chunking: big path if workspace allows (~221MB), else the
  // proven ~162MB layout. Branch depends only on ws_size (constant) ----
  const bool big = ws_size >= (size_t)230 * 1024 * 1024;
  const int acb = big ? 16 : 8;          // batches per attention chunk
  const long long acrows = (long long)acb * N_;
  const int frows = big ? 16384 : 8192;  // rows per FFN chunk

  char* P = (char*)d_ws;
  float* h = (float*)P;            P += (long long)B_ * N_ * DIM_ * 4;   // 67MB
  short* zc = (short*)P;           P += acrows * DIM_ * 2;
  short* qc = (short*)P;           P += acrows * DIM_ * 2;
  short* ffnmid = zc;              // frows*4*DIM == 2*acrows*DIM exactly
  short* zcT = (short*)P;          P += acrows * DIM_ * 2;   // also zln (FFN)
  short* zln = zcT;
  short* zp = (short*)P;           P += (long long)acb * 2 * KLIN * DIM_ * 2;
  short* kvp = (short*)P;          P += (long long)acb * 2 * KLIN * DIM_ * 2;
  short* vt = zp;                  // V^T scratch: zp is dead after kvp GEMM
  short* wq_t  = (short*)P;  P += (long long)DEPTH * DIM_ * DIM_ * 2;
  short* wkv_t = (short*)P;  P += (long long)DEPTH * 2 * DIM_ * DIM_ * 2;
  short* wo_t  = (short*)P;  P += (long long)DEPTH * DIM_ * DIM_ * 2;
  short* w1_t  = (short*)P;  P += (long long)DEPTH * 4 * DIM_ * DIM_ * 2;
  short* w2_t  = (short*)P;  P += (long long)DEPTH * 4 * DIM_ * DIM_ * 2;
  short* pkv_t = (short*)P;  P += (long long)DEPTH * 2 * KLIN * N_ * 2;
  short* emb_wt = (short*)P; P += (long long)DIM_ * INDIM * 2;
  short* x_bf  = (short*)P;  P += (long long)B_ * N_ * INDIM * 2;
  float* partial = (float*)P; P += (long long)B_ * 16 * DIM_ * 4;
  float* pooled  = (float*)P;

  const float scale = 0.125f;
  const long long WQS = (long long)DIM_ * DIM_;        // 262144
  const long long KVS = (long long)2 * KLIN * DIM_;    // 262144

  // ---- converts ----
  auto tconv = [&](const float* s, short* d, int R, int C, long long ss,
                   long long sd, int b) {
    hipLaunchKernelGGL(tconv_k, dim3(C / 32, R / 32, b), dim3(256), 0, stream,
                       s, d, R, C, ss, sd);
  };
  tconv(wq, wq_t, DIM_, DIM_, WQS, WQS, DEPTH);
  tconv(wk, wkv_t, DIM_, DIM_, WQS, 2 * WQS, DEPTH);
  tconv(wv, wkv_t + WQS, DIM_, DIM_, WQS, 2 * WQS, DEPTH);
  tconv(wo, wo_t, DIM_, DIM_, WQS, WQS, DEPTH);
  tconv(w1, w1_t, DIM_, 4 * DIM_, 4 * WQS, 4 * WQS, DEPTH);
  tconv(w2, w2_t, 4 * DIM_, DIM_, 4 * WQS, 4 * WQS, DEPTH);
  tconv(pk, pkv_t, N_, KLIN, (long long)N_ * KLIN, (long long)2 * KLIN * N_, DEPTH);
  tconv(pv, pkv_t + (long long)KLIN * N_, N_, KLIN, (long long)N_ * KLIN,
        (long long)2 * KLIN * N_, DEPTH);
  tconv(emb_w, emb_wt, INDIM, DIM_, 0, 0, 1);
  hipLaunchKernelGGL(cconv_k, dim3((B_ * N_ * INDIM / 8 + 255) / 256),
                     dim3(256), 0, stream, x, x_bf, B_ * N_ * INDIM / 8);

  // ---- embedding: h = x@emb_w + emb_b + pos ----
  hipLaunchKernelGGL((gemm_bf<0, 128, 128>), dim3(DIM_ / 128, B_ * N_ / 128, 1),
                     dim3(256), 0, stream, x_bf, emb_wt, emb_b, pos, (void*)h,
                     B_ * N_, DIM_, INDIM, INDIM, INDIM, DIM_, 0LL, 0LL, 0LL,
                     0, 0LL, 2, N_);

  for (int i = 0; i < DEPTH; ++i) {
    const short* wq_i  = wq_t + i * WQS;
    const short* wkv_i = wkv_t + i * 2 * WQS;
    const short* wo_i  = wo_t + i * WQS;
    const short* w1_i  = w1_t + (long long)i * 4 * WQS;
    const short* w2_i  = w2_t + (long long)i * 4 * WQS;
    const short* pkv_i = pkv_t + (long long)i * 2 * KLIN * N_;

    // ---- attention, B_/acb chunks ----
    for (int c = 0; c < B_ / acb; ++c) {
      float* hc = h + (long long)c * acrows * DIM_;
      hipLaunchKernelGGL(ln_k, dim3(acrows / 4), dim3(256), 0, stream, hc,
                         ln1_s + i * DIM_, ln1_b + i * DIM_, zc);
      // zcT[b] = zc[b]^T
      hipLaunchKernelGGL(tpose_k, dim3(DIM_ / 64, N_ / 64, acb), dim3(256), 0,
                         stream, zc, zcT, N_, DIM_, (long long)N_ * DIM_,
                         (long long)DIM_ * N_);
      // qc = zc @ wq  (8-phase 256x256)
      hipLaunchKernelGGL((gemm8<1, 256, 256, 0>),
                         dim3(DIM_ / 256, (int)(acrows / 256), 1), dim3(512), 0,
                         stream, zc, wq_i, nullptr, nullptr, (void*)qc,
                         (int)acrows, DIM_, DIM_, 0LL, 0LL, 0LL, 0, 0LL);
      // zp[b] = pkv^T @ zc[b]  (2-phase 64x128, batched — proven R5 config)
      hipLaunchKernelGGL((gemm_bf<1, 64, 128>), dim3(DIM_ / 128, 512 / 64, acb),
                         dim3(256), 0, stream, pkv_i, zcT, nullptr, nullptr,
                         (void*)zp, 512, DIM_, N_, N_, N_, DIM_, 0LL,
                         (long long)DIM_ * N_, KVS, 0, 0LL, 0, 0);
      // kvp[b] = zp[b] @ [wk | wv]  (B dual by output row — proven R5 config)
      hipLaunchKernelGGL((gemm_bf<1, 64, 128>), dim3(DIM_ / 128, 512 / 64, acb),
                         dim3(256), 0, stream, zp, wkv_i, nullptr, nullptr,
                         (void*)kvp, 512, DIM_, DIM_, DIM_, DIM_, DIM_, KVS,
                         0LL, KVS, KLIN, (long long)WQS, 0, 0);
      // vt[b] = V[b]^T  (zp is dead now; conflict-free global transpose)
      hipLaunchKernelGGL(tpose_k, dim3(DIM_ / 64, KLIN / 64, acb), dim3(256), 0,
                         stream, kvp + (long long)KLIN * DIM_, vt, KLIN, DIM_,
                         KVS, (long long)DIM_ * KLIN);
      // fused attention in-place on qc (QBLK=64, 256 threads, 2 blocks/CU)
      hipLaunchKernelGGL(attn_k, dim3(N_ / 64, HEADS, acb), dim3(256), 0,
                         stream, qc, kvp, vt, scale);
      // h += qc @ wo + wo_b  (8-phase 256x256)
      hipLaunchKernelGGL((gemm8<0, 256, 256, 2>),
                         dim3(DIM_ / 256, (int)(acrows / 256), 1), dim3(512), 0,
                         stream, qc, wo_i, wo_b + i * DIM_, hc, (void*)hc,
                         (int)acrows, DIM_, DIM_, 0LL, 0LL, 0LL, 0, 0LL);
    }

    // ---- FFN, (B_*N_)/frows chunks ----
    for (int r0 = 0; r0 < B_ * N_; r0 += frows) {
      float* hr = h + (long long)r0 * DIM_;
      hipLaunchKernelGGL(ln_k, dim3(frows / 4), dim3(256), 0, stream, hr,
                         ln2_s + i * DIM_, ln2_b + i * DIM_, zln);
      // ffnmid = gelu(zln @ w1 + b1)  (merged 2-phase 128x128, 2/CU)
      hipLaunchKernelGGL((gemm8m<1, 128, 128, 3>),
                         dim3(4 * DIM_ / 128, frows / 128, 1), dim3(512), 0,
                         stream, zln, w1_i, b1 + (long long)i * 4 * DIM_,
                         nullptr, (void*)ffnmid, frows, 4 * DIM_, DIM_, 0LL,
                         0LL, 0LL, 0, 0LL);
      // h += ffnmid @ w2 + b2  (merged 2-phase 128x128, 2/CU)
      hipLaunchKernelGGL((gemm8m<0, 128, 128, 2>),
                         dim3(DIM_ / 128, frows / 128, 1), dim3(512), 0,
                         stream, ffnmid, w2_i, b2 + (long long)i * DIM_, hr,
                         (void*)hr, frows, DIM_, 4 * DIM_, 0LL, 0LL, 0LL, 0,
                         0LL);
    }
  }

  hipLaunchKernelGGL(pool1_k, dim3(16, B_), dim3(256), 0, stream, h, partial);
  hipLaunchKernelGGL(pool2_k, dim3(B_), dim3(256), 0, stream, partial, pooled);
  hipLaunchKernelGGL(fc_k, dim3(1), dim3(64), 0, stream, pooled, fc_w, fc_b,
                     out);
}

// Round 11
// 1805.797 us; speedup vs baseline: 1.0338x; 1.0338x over previous
//
#include <hip/hip_runtime.h>
#include <math.h>

// ---------------- constants ----------------
#define B_    16
#define N_    2048
#define INDIM 64
#define DIM_  512
#define HEADS 8
#define DEPTH 4
#define KLIN  256
#define NCLS  2
#define DH    64
#define EPSF  1e-5f

typedef __attribute__((ext_vector_type(8))) short short8v;
typedef __attribute__((ext_vector_type(4))) short short4v;
typedef __attribute__((ext_vector_type(4))) float f32x4;

#define SBAR() __builtin_amdgcn_sched_barrier(0)

// fp32 -> bf16 round-to-nearest-even (finite inputs)
__device__ __forceinline__ short f2bf(float f) {
  unsigned u = __float_as_uint(f);
  u += 0x7FFFu + ((u >> 16) & 1u);
  return (short)(u >> 16);
}
// bf16 -> fp32
__device__ __forceinline__ float bf2f(short s) {
  return __uint_as_float((unsigned)(unsigned short)s << 16);
}

__device__ __forceinline__ float wave_sum(float v) {
  #pragma unroll
  for (int o = 32; o > 0; o >>= 1) v += __shfl_xor(v, o);
  return v;
}

// tanh-GELU via sigmoid identity (~7 VALU vs ~45+ libm tanhf)
__device__ __forceinline__ float gelu_tanh(float x) {
  float u = x * (1.5957691216057308f + 0.07135481627f * x * x);
  return x / (1.f + __expf(-u));
}

// async global->LDS, 16B per lane; LDS dest = wave-uniform base + lane*16
__device__ __forceinline__ void gl_lds16(const short* g, short* l) {
  __builtin_amdgcn_global_load_lds(
      (const __attribute__((address_space(1))) unsigned int*)g,
      (__attribute__((address_space(3))) unsigned int*)l, 16, 0, 0);
}

// ---------------- converts (once per launch) ----------------
__global__ __launch_bounds__(256) void tconv_k(const float* __restrict__ src,
                                               short* __restrict__ dst, int R,
                                               int C, long long sSrc,
                                               long long sDst) {
  __shared__ float tile[32][33];
  int c0 = blockIdx.x * 32, r0 = blockIdx.y * 32;
  src += (long long)blockIdx.z * sSrc;
  dst += (long long)blockIdx.z * sDst;
  int tx = threadIdx.x & 31, ty = threadIdx.x >> 5;
  #pragma unroll
  for (int rr = 0; rr < 4; ++rr)
    tile[ty + rr * 8][tx] = src[(long long)(r0 + ty + rr * 8) * C + c0 + tx];
  __syncthreads();
  #pragma unroll
  for (int rr = 0; rr < 4; ++rr) {
    int c = ty + rr * 8;
    dst[(long long)(c0 + c) * R + r0 + tx] = f2bf(tile[tx][c]);
  }
}

__global__ __launch_bounds__(256) void cconv_k(const float* __restrict__ src,
                                               short* __restrict__ dst,
                                               int n8) {
  int i = blockIdx.x * 256 + threadIdx.x;
  if (i < n8) {
    const float* s = src + (long long)i * 8;
    float4 a = *(const float4*)s, c = *(const float4*)(s + 4);
    short8v o = {f2bf(a.x), f2bf(a.y), f2bf(a.z), f2bf(a.w),
                 f2bf(c.x), f2bf(c.y), f2bf(c.z), f2bf(c.w)};
    *(short8v*)(dst + (long long)i * 8) = o;
  }
}

// ---------------- bf16 tile transpose: [R][C] -> [C][R], batched ----------
__global__ __launch_bounds__(256) void tpose_k(const short* __restrict__ src,
                                               short* __restrict__ dst, int R,
                                               int C, long long sSrc,
                                               long long sDst) {
  __shared__ __align__(16) short tile[64][72];
  int c0 = blockIdx.x * 64, r0 = blockIdx.y * 64;
  src += (long long)blockIdx.z * sSrc;
  dst += (long long)blockIdx.z * sDst;
  int t = threadIdx.x;
  #pragma unroll
  for (int rep = 0; rep < 2; ++rep) {
    int row = rep * 32 + (t >> 3), c8 = (t & 7) * 8;
    *(short8v*)&tile[row][c8] =
        *(const short8v*)(src + (long long)(r0 + row) * C + c0 + c8);
  }
  __syncthreads();
  #pragma unroll
  for (int rep = 0; rep < 2; ++rep) {
    int c = rep * 32 + (t >> 3), r8 = (t & 7) * 8;
    short8v o;
    #pragma unroll
    for (int j = 0; j < 8; ++j) o[j] = tile[r8 + j][c];
    *(short8v*)(dst + (long long)(c0 + c) * R + r0 + r8) = o;
  }
}

// ---------------- LayerNorm: bf16 in, bf16 out ----------------
__global__ __launch_bounds__(256) void ln_k(const short* __restrict__ h,
                                            const float* __restrict__ s,
                                            const float* __restrict__ b,
                                            short* __restrict__ z) {
  int lane = threadIdx.x & 63;
  long long row = ((long long)blockIdx.x << 2) + (threadIdx.x >> 6);
  const short* hr = h + row * DIM_ + lane * 8;
  short8v hv = *(const short8v*)hr;
  float x[8];
  #pragma unroll
  for (int i = 0; i < 8; ++i) x[i] = bf2f(hv[i]);
  float sum = 0.f;
  #pragma unroll
  for (int i = 0; i < 8; ++i) sum += x[i];
  sum = wave_sum(sum);
  float mu = sum * (1.f / DIM_);
  float d[8];
  #pragma unroll
  for (int i = 0; i < 8; ++i) d[i] = x[i] - mu;
  float vs = 0.f;
  #pragma unroll
  for (int i = 0; i < 8; ++i) vs += d[i] * d[i];
  vs = wave_sum(vs);
  float rstd = rsqrtf(vs * (1.f / DIM_) + EPSF);
  const float* sp = s + lane * 8;
  const float* bp = b + lane * 8;
  float4 s0 = *(const float4*)sp, s1 = *(const float4*)(sp + 4);
  float4 b0 = *(const float4*)bp, b1 = *(const float4*)(bp + 4);
  float o[8];
  o[0] = d[0] * rstd * s0.x + b0.x; o[1] = d[1] * rstd * s0.y + b0.y;
  o[2] = d[2] * rstd * s0.z + b0.z; o[3] = d[3] * rstd * s0.w + b0.w;
  o[4] = d[4] * rstd * s1.x + b1.x; o[5] = d[5] * rstd * s1.y + b1.y;
  o[6] = d[6] * rstd * s1.z + b1.z; o[7] = d[7] * rstd * s1.w + b1.w;
  short8v ov = {f2bf(o[0]), f2bf(o[1]), f2bf(o[2]), f2bf(o[3]),
                f2bf(o[4]), f2bf(o[5]), f2bf(o[6]), f2bf(o[7])};
  *(short8v*)(z + row * DIM_ + lane * 8) = ov;
}

// ---------------- bf16 MFMA GEMM, 2-phase pipeline (small shapes) --------
// epi: 0 none; 1 +bias; 2 +bias+resid[(m%resMod)*ldc+n] (fp32); 3 gelu(+bias)
template <int OUTBF, int BM, int BN>
__global__ __launch_bounds__(256) void gemm_bf(
    const short* __restrict__ A, const short* __restrict__ Bsrc,
    const float* __restrict__ bias, const float* __restrict__ resid,
    void* __restrict__ Cv, int M, int N, int K, int lda, int ldb, int ldc,
    long long sAb, long long sBb, long long sCb, int dualThresh,
    long long dualOff, int epi, int resMod) {
  constexpr int MT = BM / 32;   // frag rows per wave
  constexpr int NT = BN / 32;   // frag cols per wave
  constexpr int NLD = BM / 32 + BN / 32;  // global_load_lds per thread / tile
  int zz = blockIdx.z;
  A += (long long)zz * sAb;
  Bsrc += (long long)zz * sBb;
  int bm = blockIdx.y * BM, bn = blockIdx.x * BN;
  if (dualThresh && bm >= dualThresh) Bsrc += dualOff;
  int t = threadIdx.x;
  __shared__ __align__(16) short Alds[2][BM * 64];
  __shared__ __align__(16) short Blds[2][BN * 64];
  int lane = t & 63, wid = t >> 6;
  int lr = lane & 15, q = lane >> 4;
  int wm = (wid >> 1) * (BM / 2), wn = (wid & 1) * (BN / 2);
  int rl = lane >> 3;          // row within 8-row group
  int cs = (lane & 7) ^ rl;    // swizzled source chunk
  f32x4 acc[MT][NT] = {};

  // stage one BK=64 tile (A + B) into LDS buffer `buf`
  auto stage = [&](int buf, int k0) {
    #pragma unroll
    for (int i = 0; i < BM / 32; ++i) {
      int rb = i * 32 + wid * 8;
      gl_lds16(A + (long long)(bm + rb + rl) * lda + k0 + cs * 8,
               &Alds[buf][rb * 64]);
    }
    #pragma unroll
    for (int i = 0; i < BN / 32; ++i) {
      int rb = i * 32 + wid * 8;
      gl_lds16(Bsrc + (long long)(bn + rb + rl) * ldb + k0 + cs * 8,
               &Blds[buf][rb * 64]);
    }
  };

  stage(0, 0);  // prologue: tile 0 in flight
  int cur = 0;
  for (int k0 = 0; k0 < K; k0 += 64, cur ^= 1) {
    if (k0 + 64 < K) {
      stage(cur ^ 1, k0 + 64);  // prefetch next tile (overlaps MFMA below)
      SBAR();  // pin issue above the counted wait
      asm volatile("s_waitcnt vmcnt(%0)" ::"n"(NLD) : "memory");  // tile k0 done
    } else {
      SBAR();
      asm volatile("s_waitcnt vmcnt(0)" ::: "memory");
    }
    __builtin_amdgcn_s_barrier();        // everyone's tile-k0 loads landed
    SBAR();                              // keep ds_reads below the barrier
    #pragma unroll
    for (int kk2 = 0; kk2 < 2; ++kk2) {
      short8v af[MT], bfr[NT];
      #pragma unroll
      for (int mi = 0; mi < MT; ++mi)
        af[mi] = *(const short8v*)&Alds[cur][(wm + mi * 16 + lr) * 64 +
                                             (((kk2 << 2) | q) ^ (lr & 7)) * 8];
      #pragma unroll
      for (int ni = 0; ni < NT; ++ni)
        bfr[ni] = *(const short8v*)&Blds[cur][(wn + ni * 16 + lr) * 64 +
                                              (((kk2 << 2) | q) ^ (lr & 7)) * 8];
      #pragma unroll
      for (int mi = 0; mi < MT; ++mi)
        #pragma unroll
        for (int ni = 0; ni < NT; ++ni)
          acc[mi][ni] = __builtin_amdgcn_mfma_f32_16x16x32_bf16(
              bfr[ni], af[mi], acc[mi][ni], 0, 0, 0);  // swapped: cols in regs
    }
    SBAR();                              // reads of buf[cur] complete here
    __builtin_amdgcn_s_barrier();        // before next iter overwrites it
  }

  #pragma unroll
  for (int mi = 0; mi < MT; ++mi) {
    int m = bm + wm + mi * 16 + lr;
    int rm = (epi == 2 && resMod) ? (m % resMod) : m;
    #pragma unroll
    for (int ni = 0; ni < NT; ++ni) {
      int nb = bn + wn + ni * 16 + q * 4;
      f32x4 v = acc[mi][ni];
      if (epi >= 1) {
        float4 bb = *(const float4*)(bias + nb);
        v[0] += bb.x; v[1] += bb.y; v[2] += bb.z; v[3] += bb.w;
      }
      if (epi == 2) {
        float4 rr = *(const float4*)(resid + (long long)rm * ldc + nb);
        v[0] += rr.x; v[1] += rr.y; v[2] += rr.z; v[3] += rr.w;
      } else if (epi == 3) {
        v[0] = gelu_tanh(v[0]); v[1] = gelu_tanh(v[1]);
        v[2] = gelu_tanh(v[2]); v[3] = gelu_tanh(v[3]);
      }
      long long base = (long long)zz * sCb + (long long)m * ldc + nb;
      if (OUTBF) {
        short4v o = {f2bf(v[0]), f2bf(v[1]), f2bf(v[2]), f2bf(v[3])};
        *(short4v*)((short*)Cv + base) = o;
      } else {
        *(float4*)((float*)Cv + base) = make_float4(v[0], v[1], v[2], v[3]);
      }
    }
  }
}

// ---------------- 8-phase bf16 MFMA GEMM (big shapes, batched) ------------
// BMxBN tile, BK=64, 512 threads = 8 waves (2M x 4N); per-wave tile
// (BM/2) x (BN/4). 4 compute phases per K-tile (quadrants). Counted
// vmcnt(LA) per K-tile, half-tile staging ring. R8 (best timed config):
// B-lo+B-hi(t+1) issued at P3. T1: bijective XCD swizzle per z-slice.
// Batched via blockIdx.z strides; dual-B row split. lda=ldb=K; ldc=N.
// EPI: 0 none; 2 bias + BF16 resid (h stream, bf16); 3 bias+gelu.
template <int OUTBF, int BM, int BN, int EPI>
__global__ __launch_bounds__(512, 2) void gemm8(
    const short* __restrict__ A, const short* __restrict__ Bt,
    const float* __restrict__ bias, const float* __restrict__ resid,
    void* __restrict__ Cv, int M, int N, int K, long long sAb, long long sBb,
    long long sCb, int dualThresh, long long dualOff) {
  constexpr int MH = BM / 64;     // 16-row frags per row-half per wave: 4 or 2
  constexpr int WCOL = BN / 4;    // cols per wave (64 or 32)
  constexpr int NT = WCOL / 16;   // 4 or 2
  constexpr int NTH = NT / 2;     // col-half frags: 2 or 1
  constexpr int LB = BN / 128;    // gl_lds per B-half: 2 or 1
  constexpr int LA = BM / 128;    // gl_lds per A-half: 2 or 1
  __shared__ __align__(16) short Alds[2][BM * 64];
  __shared__ __align__(16) short Blds[2][BN * 64];
  const int tid = threadIdx.x;
  const int lane = tid & 63, wid = tid >> 6;
  const int lr = lane & 15, q = lane >> 4;
  const int wm = (wid >> 2) * (BM / 2), wn = (wid & 3) * WCOL;
  const int rl = lane >> 3, cs = (lane & 7) ^ rl;
  const int zz = blockIdx.z;
  A += (long long)zz * sAb;
  Bt += (long long)zz * sBb;
  const int nwg = gridDim.x * gridDim.y;
  int bid = blockIdx.y * gridDim.x + blockIdx.x;
  const int nx8 = nwg >> 3, r8 = nwg & 7, xcd = bid & 7, loc = bid >> 3;
  int swz = (xcd < r8 ? xcd * (nx8 + 1) : r8 * (nx8 + 1) + (xcd - r8) * nx8)
            + loc;
  const int bm = (swz / gridDim.x) * BM, bn = (swz % gridDim.x) * BN;
  if (dualThresh && bm >= dualThresh) Bt += dualOff;
  const short* Ag = A + (long long)bm * K + cs * 8;
  const short* Bg = Bt + (long long)bn * K + cs * 8;
  f32x4 acc[2 * MH][NT] = {};

  auto stageA = [&](int slot, int h, int k0) {
    #pragma unroll
    for (int j = 0; j < LA; ++j) {
      int rb = h * (BM / 2) + j * 64 + wid * 8;
      gl_lds16(Ag + (long long)(rb + rl) * K + k0, &Alds[slot][rb * 64]);
    }
  };
  auto stageB = [&](int slot, int h, int k0) {
    #pragma unroll
    for (int j = 0; j < LB; ++j) {
      int rb = h * (BN / 2) + j * 64 + wid * 8;
      gl_lds16(Bg + (long long)(rb + rl) * K + k0, &Blds[slot][rb * 64]);
    }
  };
  auto rd = [&](const short* Ls, int row, int kk) -> short8v {
    return *(const short8v*)&Ls[row * 64 + ((((kk << 2) | q) ^ (lr & 7)) << 3)];
  };
  auto mfma4 = [&](short8v (&af)[MH][2], short8v (&bf)[NTH][2], int mo,
                   int no) {
    #pragma unroll
    for (int mi = 0; mi < MH; ++mi)
      #pragma unroll
      for (int ni = 0; ni < NTH; ++ni)
        #pragma unroll
        for (int kk = 0; kk < 2; ++kk)
          acc[mo + mi][no + ni] = __builtin_amdgcn_mfma_f32_16x16x32_bf16(
              bf[ni][kk], af[mi][kk], acc[mo + mi][no + ni], 0, 0, 0);
  };

  const int T = K >> 6;
  stageA(0, 0, 0); stageA(0, 1, 0); stageB(0, 0, 0); stageB(0, 1, 0);
  if (T > 1) {
    stageA(1, 0, 64);
    SBAR();
    asm volatile("s_waitcnt vmcnt(%0)" ::"n"(LA) : "memory");
  } else {
    SBAR();
    asm volatile("s_waitcnt vmcnt(0)" ::: "memory");
  }
  __builtin_amdgcn_s_barrier();

  for (int tt = 0; tt < T; ++tt) {
    const int s = tt & 1, ns = s ^ 1;
    const int kn = (tt + 1) << 6, kn2 = (tt + 2) << 6;
    const short* Als = Alds[s];
    const short* Bls = Blds[s];
    short8v af0[MH][2], af1[MH][2], bf0[NTH][2], bf1[NTH][2];
    // ---- P1: quadrant (row-lo x col-lo); stage A-hi(t+1) ----
    SBAR();
    #pragma unroll
    for (int mi = 0; mi < MH; ++mi)
      #pragma unroll
      for (int kk = 0; kk < 2; ++kk)
        af0[mi][kk] = rd(Als, wm + mi * 16 + lr, kk);
    #pragma unroll
    for (int ni = 0; ni < NTH; ++ni)
      #pragma unroll
      for (int kk = 0; kk < 2; ++kk)
        bf0[ni][kk] = rd(Bls, wn + ni * 16 + lr, kk);
    if (tt + 1 < T) stageA(ns, 1, kn);
    if (BN == 256) asm volatile("s_waitcnt lgkmcnt(8)" ::: "memory");
    SBAR();
    __builtin_amdgcn_s_barrier();
    asm volatile("s_waitcnt lgkmcnt(0)" ::: "memory");
    SBAR();
    __builtin_amdgcn_s_setprio(1);
    mfma4(af0, bf0, 0, 0);
    __builtin_amdgcn_s_setprio(0);
    SBAR();
    __builtin_amdgcn_s_barrier();
    // ---- P2: (row-lo x col-hi) ----
    SBAR();
    #pragma unroll
    for (int ni = 0; ni < NTH; ++ni)
      #pragma unroll
      for (int kk = 0; kk < 2; ++kk)
        bf1[ni][kk] = rd(Bls, wn + (NTH + ni) * 16 + lr, kk);
    SBAR();
    __builtin_amdgcn_s_barrier();
    asm volatile("s_waitcnt lgkmcnt(0)" ::: "memory");
    SBAR();
    __builtin_amdgcn_s_setprio(1);
    mfma4(af0, bf1, 0, NTH);
    __builtin_amdgcn_s_setprio(0);
    SBAR();
    __builtin_amdgcn_s_barrier();
    // ---- P3: (row-hi x col-lo); stage B-lo(t+1) + B-hi(t+1) ----
    SBAR();
    #pragma unroll
    for (int mi = 0; mi < MH; ++mi)
      #pragma unroll
      for (int kk = 0; kk < 2; ++kk)
        af1[mi][kk] = rd(Als, wm + MH * 16 + mi * 16 + lr, kk);
    if (tt + 1 < T) { stageB(ns, 0, kn); stageB(ns, 1, kn); }
    SBAR();
    __builtin_amdgcn_s_barrier();
    asm volatile("s_waitcnt lgkmcnt(0)" ::: "memory");
    SBAR();
    __builtin_amdgcn_s_setprio(1);
    mfma4(af1, bf0, MH, 0);
    __builtin_amdgcn_s_setprio(0);
    SBAR();
    __builtin_amdgcn_s_barrier();
    // ---- P4: (row-hi x col-hi); stage A-lo(t+2); counted wait ----
    SBAR();
    if (tt + 2 < T) stageA(s, 0, kn2);
    SBAR();
    __builtin_amdgcn_s_barrier();
    __builtin_amdgcn_s_setprio(1);
    mfma4(af1, bf1, MH, NTH);
    __builtin_amdgcn_s_setprio(0);
    if (tt + 2 < T) {
      SBAR();
      asm volatile("s_waitcnt vmcnt(%0)" ::"n"(LA) : "memory");  // t+1 landed
    } else if (tt + 1 < T) {
      SBAR();
      asm volatile("s_waitcnt vmcnt(0)" ::: "memory");  // final tile landed
    }
    SBAR();
    __builtin_amdgcn_s_barrier();
  }

  #pragma unroll
  for (int mi = 0; mi < 2 * MH; ++mi) {
    int m = bm + wm + mi * 16 + lr;
    #pragma unroll
    for (int nj = 0; nj < NT; ++nj) {
      int nb = bn + wn + nj * 16 + q * 4;
      f32x4 v = acc[mi][nj];
      if (EPI >= 1) {
        float4 bb = *(const float4*)(bias + nb);
        v[0] += bb.x; v[1] += bb.y; v[2] += bb.z; v[3] += bb.w;
      }
      if (EPI == 2) {
        const short* rp = (const short*)resid;
        short4v rr = *(const short4v*)(rp + (long long)m * N + nb);
        v[0] += bf2f(rr[0]); v[1] += bf2f(rr[1]);
        v[2] += bf2f(rr[2]); v[3] += bf2f(rr[3]);
      } else if (EPI == 3) {
        v[0] = gelu_tanh(v[0]); v[1] = gelu_tanh(v[1]);
        v[2] = gelu_tanh(v[2]); v[3] = gelu_tanh(v[3]);
      }
      long long base = (long long)zz * sCb + (long long)m * N + nb;
      if (OUTBF) {
        short4v o = {f2bf(v[0]), f2bf(v[1]), f2bf(v[2]), f2bf(v[3])};
        *(short4v*)((short*)Cv + base) = o;
      } else {
        *(float4*)((float*)Cv + base) = make_float4(v[0], v[1], v[2], v[3]);
      }
    }
  }
}

// ---------------- merged 2-phase variant of gemm8 (for small tiles) -------
// Same staging ring and vmcnt values as gemm8; 4 compute quadrants merged
// into 2 row-half phases. R8 config (best timed): ALL of tile t+1 staged in
// P1; A-lo(t+2) in P2. EPI==2 = bias + BF16 resid (h stream).
template <int OUTBF, int BM, int BN, int EPI>
__global__ __launch_bounds__(512, 2) void gemm8m(
    const short* __restrict__ A, const short* __restrict__ Bt,
    const float* __restrict__ bias, const float* __restrict__ resid,
    void* __restrict__ Cv, int M, int N, int K, long long sAb, long long sBb,
    long long sCb, int dualThresh, long long dualOff) {
  constexpr int MH = BM / 64;
  constexpr int WCOL = BN / 4;
  constexpr int NT = WCOL / 16;
  constexpr int NTH = NT / 2;
  constexpr int LB = BN / 128;
  constexpr int LA = BM / 128;
  __shared__ __align__(16) short Alds[2][BM * 64];
  __shared__ __align__(16) short Blds[2][BN * 64];
  const int tid = threadIdx.x;
  const int lane = tid & 63, wid = tid >> 6;
  const int lr = lane & 15, q = lane >> 4;
  const int wm = (wid >> 2) * (BM / 2), wn = (wid & 3) * WCOL;
  const int rl = lane >> 3, cs = (lane & 7) ^ rl;
  const int zz = blockIdx.z;
  A += (long long)zz * sAb;
  Bt += (long long)zz * sBb;
  const int nwg = gridDim.x * gridDim.y;
  int bid = blockIdx.y * gridDim.x + blockIdx.x;
  const int nx8 = nwg >> 3, r8 = nwg & 7, xcd = bid & 7, loc = bid >> 3;
  int swz = (xcd < r8 ? xcd * (nx8 + 1) : r8 * (nx8 + 1) + (xcd - r8) * nx8)
            + loc;
  const int bm = (swz / gridDim.x) * BM, bn = (swz % gridDim.x) * BN;
  if (dualThresh && bm >= dualThresh) Bt += dualOff;
  const short* Ag = A + (long long)bm * K + cs * 8;
  const short* Bg = Bt + (long long)bn * K + cs * 8;
  f32x4 acc[2 * MH][NT] = {};

  auto stageA = [&](int slot, int h, int k0) {
    #pragma unroll
    for (int j = 0; j < LA; ++j) {
      int rb = h * (BM / 2) + j * 64 + wid * 8;
      gl_lds16(Ag + (long long)(rb + rl) * K + k0, &Alds[slot][rb * 64]);
    }
  };
  auto stageB = [&](int slot, int h, int k0) {
    #pragma unroll
    for (int j = 0; j < LB; ++j) {
      int rb = h * (BN / 2) + j * 64 + wid * 8;
      gl_lds16(Bg + (long long)(rb + rl) * K + k0, &Blds[slot][rb * 64]);
    }
  };
  auto rd = [&](const short* Ls, int row, int kk) -> short8v {
    return *(const short8v*)&Ls[row * 64 + ((((kk << 2) | q) ^ (lr & 7)) << 3)];
  };
  auto mfma4 = [&](short8v (&af)[MH][2], short8v (&bf)[NTH][2], int mo,
                   int no) {
    #pragma unroll
    for (int mi = 0; mi < MH; ++mi)
      #pragma unroll
      for (int ni = 0; ni < NTH; ++ni)
        #pragma unroll
        for (int kk = 0; kk < 2; ++kk)
          acc[mo + mi][no + ni] = __builtin_amdgcn_mfma_f32_16x16x32_bf16(
              bf[ni][kk], af[mi][kk], acc[mo + mi][no + ni], 0, 0, 0);
  };

  const int T = K >> 6;
  stageA(0, 0, 0); stageA(0, 1, 0); stageB(0, 0, 0); stageB(0, 1, 0);
  if (T > 1) {
    stageA(1, 0, 64);
    SBAR();
    asm volatile("s_waitcnt vmcnt(%0)" ::"n"(LA) : "memory");
  } else {
    SBAR();
    asm volatile("s_waitcnt vmcnt(0)" ::: "memory");
  }
  __builtin_amdgcn_s_barrier();

  for (int tt = 0; tt < T; ++tt) {
    const int s = tt & 1, ns = s ^ 1;
    const int kn = (tt + 1) << 6, kn2 = (tt + 2) << 6;
    const short* Als = Alds[s];
    const short* Bls = Blds[s];
    short8v af0[MH][2], af1[MH][2], bf0[NTH][2], bf1[NTH][2];
    // ---- P1 (merged): row-lo x all cols; stage ALL of tile t+1 ----
    SBAR();
    #pragma unroll
    for (int mi = 0; mi < MH; ++mi)
      #pragma unroll
      for (int kk = 0; kk < 2; ++kk)
        af0[mi][kk] = rd(Als, wm + mi * 16 + lr, kk);
    #pragma unroll
    for (int ni = 0; ni < NTH; ++ni)
      #pragma unroll
      for (int kk = 0; kk < 2; ++kk) {
        bf0[ni][kk] = rd(Bls, wn + ni * 16 + lr, kk);
        bf1[ni][kk] = rd(Bls, wn + (NTH + ni) * 16 + lr, kk);
      }
    if (tt + 1 < T) {
      stageA(ns, 1, kn);
      stageB(ns, 0, kn);
      stageB(ns, 1, kn);
    }
    SBAR();
    __builtin_amdgcn_s_barrier();
    asm volatile("s_waitcnt lgkmcnt(0)" ::: "memory");
    SBAR();
    __builtin_amdgcn_s_setprio(1);
    mfma4(af0, bf0, 0, 0);
    mfma4(af0, bf1, 0, NTH);
    __builtin_amdgcn_s_setprio(0);
    SBAR();
    __builtin_amdgcn_s_barrier();
    // ---- P2 (merged): row-hi x all cols; stage A-lo(t+2) ----
    SBAR();
    #pragma unroll
    for (int mi = 0; mi < MH; ++mi)
      #pragma unroll
      for (int kk = 0; kk < 2; ++kk)
        af1[mi][kk] = rd(Als, wm + MH * 16 + mi * 16 + lr, kk);
    if (tt + 2 < T) stageA(s, 0, kn2);
    SBAR();
    __builtin_amdgcn_s_barrier();
    asm volatile("s_waitcnt lgkmcnt(0)" ::: "memory");
    SBAR();
    __builtin_amdgcn_s_setprio(1);
    mfma4(af1, bf0, MH, 0);
    mfma4(af1, bf1, MH, NTH);
    __builtin_amdgcn_s_setprio(0);
    if (tt + 2 < T) {
      SBAR();
      asm volatile("s_waitcnt vmcnt(%0)" ::"n"(LA) : "memory");  // t+1 landed
    } else if (tt + 1 < T) {
      SBAR();
      asm volatile("s_waitcnt vmcnt(0)" ::: "memory");
    }
    SBAR();
    __builtin_amdgcn_s_barrier();
  }

  #pragma unroll
  for (int mi = 0; mi < 2 * MH; ++mi) {
    int m = bm + wm + mi * 16 + lr;
    #pragma unroll
    for (int nj = 0; nj < NT; ++nj) {
      int nb = bn + wn + nj * 16 + q * 4;
      f32x4 v = acc[mi][nj];
      if (EPI >= 1) {
        float4 bb = *(const float4*)(bias + nb);
        v[0] += bb.x; v[1] += bb.y; v[2] += bb.z; v[3] += bb.w;
      }
      if (EPI == 2) {
        const short* rp = (const short*)resid;
        short4v rr = *(const short4v*)(rp + (long long)m * N + nb);
        v[0] += bf2f(rr[0]); v[1] += bf2f(rr[1]);
        v[2] += bf2f(rr[2]); v[3] += bf2f(rr[3]);
      } else if (EPI == 3) {
        v[0] = gelu_tanh(v[0]); v[1] = gelu_tanh(v[1]);
        v[2] = gelu_tanh(v[2]); v[3] = gelu_tanh(v[3]);
      }
      long long base = (long long)zz * sCb + (long long)m * N + nb;
      if (OUTBF) {
        short4v o = {f2bf(v[0]), f2bf(v[1]), f2bf(v[2]), f2bf(v[3])};
        *(short4v*)((short*)Cv + base) = o;
      } else {
        *(float4*)((float*)Cv + base) = make_float4(v[0], v[1], v[2], v[3]);
      }
    }
  }
}

// ---------------- fused Linformer attention, bf16 MFMA ----------------
// QBLK=64, 256 threads, LDS 78KB -> 2 blocks/CU (proven R3 config).
__global__ __launch_bounds__(256) void attn_k(short* __restrict__ qc,
                                              const short* __restrict__ kvp,
                                              const short* __restrict__ vt,
                                              float scale) {
  int n0 = blockIdx.x * 64, hh = blockIdx.y, b = blockIdx.z;
  int t = threadIdx.x;
  int lane = t & 63, w = t >> 6;
  int lr = lane & 15, qd = lane >> 4;

  __shared__ __align__(16) short Qlds[64][72];
  __shared__ __align__(16) short Kbuf[256 * 72];  // K, then aliased as P
  __shared__ __align__(16) short Vt[64][264];
  auto Klds = (short(*)[72])Kbuf;
  auto Plds = (short(*)[264])Kbuf;

  short* qptr = qc + (long long)b * N_ * DIM_ + hh * DH;
  const short* kptr = kvp + (long long)b * 2 * KLIN * DIM_ + hh * DH;
  const short* vtp = vt + (long long)b * DIM_ * KLIN + (long long)hh * DH * KLIN;

  #pragma unroll
  for (int rep = 0; rep < 2; ++rep) {
    int L = rep * 256 + t, row = L >> 3, c8 = (L & 7) << 3;
    *(short8v*)&Qlds[row][c8] =
        *(const short8v*)(qptr + (long long)(n0 + row) * DIM_ + c8);
  }
  #pragma unroll
  for (int rep = 0; rep < 8; ++rep) {
    int L = rep * 256 + t, row = L >> 3, c8 = (L & 7) << 3;
    *(short8v*)&Klds[row][c8] =
        *(const short8v*)(kptr + (long long)row * DIM_ + c8);
  }
  // V^T rows (dh-major, 256 k-cols each): coalesced, conflict-free staging
  #pragma unroll
  for (int rep = 0; rep < 8; ++rep) {
    int L = rep * 256 + t, row = L >> 5, c8 = (L & 31) << 3;
    *(short8v*)&Vt[row][c8] =
        *(const short8v*)(vtp + (long long)row * KLIN + c8);
  }
  __syncthreads();

  short8v qa0 = *(const short8v*)&Qlds[16 * w + lr][qd * 8];
  short8v qa1 = *(const short8v*)&Qlds[16 * w + lr][32 + qd * 8];
  f32x4 sacc[16];
  #pragma unroll
  for (int nt = 0; nt < 16; ++nt) {
    short8v b0 = *(const short8v*)&Klds[nt * 16 + lr][qd * 8];
    short8v b1 = *(const short8v*)&Klds[nt * 16 + lr][32 + qd * 8];
    f32x4 acc = {};
    acc = __builtin_amdgcn_mfma_f32_16x16x32_bf16(b0, qa0, acc, 0, 0, 0);
    acc = __builtin_amdgcn_mfma_f32_16x16x32_bf16(b1, qa1, acc, 0, 0, 0);
    sacc[nt] = acc;
  }

  // softmax over the lane-local row slice (64 vals) + 2-shfl qd reduction.
  float mx = -1e30f;
  #pragma unroll
  for (int nt = 0; nt < 16; ++nt)
    #pragma unroll
    for (int r = 0; r < 4; ++r) mx = fmaxf(mx, sacc[nt][r]);
  mx = fmaxf(mx, __shfl_xor(mx, 16));
  mx = fmaxf(mx, __shfl_xor(mx, 32));
  float rs = 0.f;
  #pragma unroll
  for (int nt = 0; nt < 16; ++nt)
    #pragma unroll
    for (int r = 0; r < 4; ++r) {
      float e = __expf((sacc[nt][r] - mx) * scale);
      sacc[nt][r] = e;
      rs += e;
    }
  rs += __shfl_xor(rs, 16);
  rs += __shfl_xor(rs, 32);
  float inv = 1.f / rs;

  __syncthreads();  // Klds reads done; reuse as Plds
  #pragma unroll
  for (int nt = 0; nt < 16; ++nt) {
    short4v p = {f2bf(sacc[nt][0] * inv), f2bf(sacc[nt][1] * inv),
                 f2bf(sacc[nt][2] * inv), f2bf(sacc[nt][3] * inv)};
    *(short4v*)&Plds[16 * w + lr][nt * 16 + qd * 4] = p;
  }
  __syncthreads();

  f32x4 out[4] = {};
  #pragma unroll
  for (int k0 = 0; k0 < 8; ++k0) {
    short8v ap = *(const short8v*)&Plds[16 * w + lr][k0 * 32 + qd * 8];
    #pragma unroll
    for (int n2 = 0; n2 < 4; ++n2) {
      short8v bv = *(const short8v*)&Vt[n2 * 16 + lr][k0 * 32 + qd * 8];
      out[n2] =
          __builtin_amdgcn_mfma_f32_16x16x32_bf16(bv, ap, out[n2], 0, 0, 0);
    }
  }

  long long rowoff = (long long)(n0 + 16 * w + lr) * DIM_;
  #pragma unroll
  for (int n2 = 0; n2 < 4; ++n2) {
    short4v o = {f2bf(out[n2][0]), f2bf(out[n2][1]), f2bf(out[n2][2]),
                 f2bf(out[n2][3])};
    *(short4v*)(qptr + rowoff + n2 * 16 + qd * 4) = o;
  }
}

// ---------------- two-stage mean pool (bf16 h) ----------------
__global__ __launch_bounds__(256) void pool1_k(const short* __restrict__ h,
                                               float* __restrict__ partial) {
  int stripe = blockIdx.x, b = blockIdx.y;
  int c8 = (threadIdx.x & 63) * 8, grp = threadIdx.x >> 6;  // 4 row-groups
  const short* base =
      h + ((long long)b * N_ + stripe * 128 + grp * 32) * DIM_ + c8;
  float acc[8] = {};
  for (int r = 0; r < 32; ++r) {
    short8v v = *(const short8v*)(base + (long long)r * DIM_);
    #pragma unroll
    for (int i = 0; i < 8; ++i) acc[i] += bf2f(v[i]);
  }
  __shared__ float red[3][512];
  if (grp) {
    *(float4*)&red[grp - 1][c8] = make_float4(acc[0], acc[1], acc[2], acc[3]);
    *(float4*)&red[grp - 1][c8 + 4] =
        make_float4(acc[4], acc[5], acc[6], acc[7]);
  }
  __syncthreads();
  if (grp == 0) {
    float o[8];
    #pragma unroll
    for (int i = 0; i < 8; ++i)
      o[i] = acc[i] + red[0][c8 + i] + red[1][c8 + i] + red[2][c8 + i];
    float* pp = &partial[((long long)b * 16 + stripe) * DIM_ + c8];
    *(float4*)pp = make_float4(o[0], o[1], o[2], o[3]);
    *(float4*)(pp + 4) = make_float4(o[4], o[5], o[6], o[7]);
  }
}
__global__ __launch_bounds__(256) void pool2_k(const float* __restrict__ partial,
                                               float* __restrict__ pooled) {
  int b = blockIdx.x;
  for (int c = threadIdx.x; c < DIM_; c += 256) {
    float s = 0.f;
    for (int k = 0; k < 16; ++k) s += partial[((long long)b * 16 + k) * DIM_ + c];
    pooled[b * DIM_ + c] = s * (1.f / N_);
  }
}

// ---------------- final FC [16,512]@[512,2] ----------------
__global__ __launch_bounds__(64) void fc_k(const float* __restrict__ pooled,
                                           const float* __restrict__ fc_w,
                                           const float* __restrict__ fc_b,
                                           float* __restrict__ out) {
  int t = threadIdx.x;
  if (t < B_ * NCLS) {
    int b = t >> 1, c = t & 1;
    float s = fc_b[c];
    for (int d = 0; d < DIM_; ++d)
      s += pooled[b * DIM_ + d] * fc_w[d * NCLS + c];
    out[t] = s;
  }
}

extern "C" void kernel_launch(void* const* d_in, const int* in_sizes, int n_in,
                              void* d_out, int out_size, void* d_ws,
                              size_t ws_size, hipStream_t stream) {
  const float* x     = (const float*)d_in[0];
  const float* emb_w = (const float*)d_in[1];
  const float* emb_b = (const float*)d_in[2];
  const float* pos   = (const float*)d_in[3];
  const float* ln1_s = (const float*)d_in[4];
  const float* ln1_b = (const float*)d_in[5];
  const float* wq    = (const float*)d_in[6];
  const float* wk    = (const float*)d_in[7];
  const float* wv    = (const float*)d_in[8];
  const float* pk    = (const float*)d_in[9];
  const float* pv    = (const float*)d_in[10];
  const float* wo    = (const float*)d_in[11];
  const float* wo_b  = (const float*)d_in[12];
  const float* ln2_s = (const float*)d_in[13];
  const float* ln2_b = (const float*)d_in[14];
  const float* w1    = (const float*)d_in[15];
  const float* b1    = (const float*)d_in[16];
  const float* w2    = (const float*)d_in[17];
  const float* b2    = (const float*)d_in[18];
  const float* fc_w  = (const float*)d_in[19];
  const float* fc_b  = (const float*)d_in[20];
  float* out = (float*)d_out;

  const bool big = ws_size >= (size_t)230 * 1024 * 1024;
  const int acb = big ? 16 : 8;          // batches per attention chunk
  const long long acrows = (long long)acb * N_;
  const int frows = big ? 16384 : 8192;  // rows per FFN chunk

  char* P = (char*)d_ws;
  short* h = (short*)P;            P += (long long)B_ * N_ * DIM_ * 2;  // 33.5MB bf16
  short* zc = (short*)P;           P += acrows * DIM_ * 2;
  short* qc = (short*)P;           P += acrows * DIM_ * 2;
  short* ffnmid = zc;              // frows*4*DIM == 2*acrows*DIM exactly
  short* zcT = (short*)P;          P += acrows * DIM_ * 2;   // also zln (FFN)
  short* zln = zcT;
  short* zp = (short*)P;           P += (long long)acb * 2 * KLIN * DIM_ * 2;
  short* kvp = (short*)P;          P += (long long)acb * 2 * KLIN * DIM_ * 2;
  short* vt = zp;                  // V^T scratch: zp is dead after kvp GEMM
  short* wq_t  = (short*)P;  P += (long long)DEPTH * DIM_ * DIM_ * 2;
  short* wkv_t = (short*)P;  P += (long long)DEPTH * 2 * DIM_ * DIM_ * 2;
  short* wo_t  = (short*)P;  P += (long long)DEPTH * DIM_ * DIM_ * 2;
  short* w1_t  = (short*)P;  P += (long long)DEPTH * 4 * DIM_ * DIM_ * 2;
  short* w2_t  = (short*)P;  P += (long long)DEPTH * 4 * DIM_ * DIM_ * 2;
  short* pkv_t = (short*)P;  P += (long long)DEPTH * 2 * KLIN * N_ * 2;
  short* emb_wt = (short*)P; P += (long long)DIM_ * INDIM * 2;
  short* x_bf  = (short*)P;  P += (long long)B_ * N_ * INDIM * 2;
  float* partial = (float*)P; P += (long long)B_ * 16 * DIM_ * 4;
  float* pooled  = (float*)P;

  const float scale = 0.125f;
  const long long WQS = (long long)DIM_ * DIM_;        // 262144
  const long long KVS = (long long)2 * KLIN * DIM_;    // 262144

  // ---- converts ----
  auto tconv = [&](const float* s, short* d, int R, int C, long long ss,
                   long long sd, int b) {
    hipLaunchKernelGGL(tconv_k, dim3(C / 32, R / 32, b), dim3(256), 0, stream,
                       s, d, R, C, ss, sd);
  };
  tconv(wq, wq_t, DIM_, DIM_, WQS, WQS, DEPTH);
  tconv(wk, wkv_t, DIM_, DIM_, WQS, 2 * WQS, DEPTH);
  tconv(wv, wkv_t + WQS, DIM_, DIM_, WQS, 2 * WQS, DEPTH);
  tconv(wo, wo_t, DIM_, DIM_, WQS, WQS, DEPTH);
  tconv(w1, w1_t, DIM_, 4 * DIM_, 4 * WQS, 4 * WQS, DEPTH);
  tconv(w2, w2_t, 4 * DIM_, DIM_, 4 * WQS, 4 * WQS, DEPTH);
  tconv(pk, pkv_t, N_, KLIN, (long long)N_ * KLIN, (long long)2 * KLIN * N_, DEPTH);
  tconv(pv, pkv_t + (long long)KLIN * N_, N_, KLIN, (long long)N_ * KLIN,
        (long long)2 * KLIN * N_, DEPTH);
  tconv(emb_w, emb_wt, INDIM, DIM_, 0, 0, 1);
  hipLaunchKernelGGL(cconv_k, dim3((B_ * N_ * INDIM / 8 + 255) / 256),
                     dim3(256), 0, stream, x, x_bf, B_ * N_ * INDIM / 8);

  // ---- embedding: h = bf16(x@emb_w + emb_b + pos), pos resid fp32 ----
  hipLaunchKernelGGL((gemm_bf<1, 128, 128>), dim3(DIM_ / 128, B_ * N_ / 128, 1),
                     dim3(256), 0, stream, x_bf, emb_wt, emb_b, pos, (void*)h,
                     B_ * N_, DIM_, INDIM, INDIM, INDIM, DIM_, 0LL, 0LL, 0LL,
                     0, 0LL, 2, N_);

  for (int i = 0; i < DEPTH; ++i) {
    const short* wq_i  = wq_t + i * WQS;
    const short* wkv_i = wkv_t + i * 2 * WQS;
    const short* wo_i  = wo_t + i * WQS;
    const short* w1_i  = w1_t + (long long)i * 4 * WQS;
    const short* w2_i  = w2_t + (long long)i * 4 * WQS;
    const short* pkv_i = pkv_t + (long long)i * 2 * KLIN * N_;

    // ---- attention, B_/acb chunks ----
    for (int c = 0; c < B_ / acb; ++c) {
      short* hc = h + (long long)c * acrows * DIM_;
      hipLaunchKernelGGL(ln_k, dim3(acrows / 4), dim3(256), 0, stream, hc,
                         ln1_s + i * DIM_, ln1_b + i * DIM_, zc);
      // zcT[b] = zc[b]^T
      hipLaunchKernelGGL(tpose_k, dim3(DIM_ / 64, N_ / 64, acb), dim3(256), 0,
                         stream, zc, zcT, N_, DIM_, (long long)N_ * DIM_,
                         (long long)DIM_ * N_);
      // qc = zc @ wq  (8-phase 256x256)
      hipLaunchKernelGGL((gemm8<1, 256, 256, 0>),
                         dim3(DIM_ / 256, (int)(acrows / 256), 1), dim3(512), 0,
                         stream, zc, wq_i, nullptr, nullptr, (void*)qc,
                         (int)acrows, DIM_, DIM_, 0LL, 0LL, 0LL, 0, 0LL);
      // zp[b] = pkv^T @ zc[b]  (2-phase 64x128, batched — proven R5 config)
      hipLaunchKernelGGL((gemm_bf<1, 64, 128>), dim3(DIM_ / 128, 512 / 64, acb),
                         dim3(256), 0, stream, pkv_i, zcT, nullptr, nullptr,
                         (void*)zp, 512, DIM_, N_, N_, N_, DIM_, 0LL,
                         (long long)DIM_ * N_, KVS, 0, 0LL, 0, 0);
      // kvp[b] = zp[b] @ [wk | wv]  (B dual by output row — proven R5 config)
      hipLaunchKernelGGL((gemm_bf<1, 64, 128>), dim3(DIM_ / 128, 512 / 64, acb),
                         dim3(256), 0, stream, zp, wkv_i, nullptr, nullptr,
                         (void*)kvp, 512, DIM_, DIM_, DIM_, DIM_, DIM_, KVS,
                         0LL, KVS, KLIN, (long long)WQS, 0, 0);
      // vt[b] = V[b]^T  (zp is dead now; conflict-free global transpose)
      hipLaunchKernelGGL(tpose_k, dim3(DIM_ / 64, KLIN / 64, acb), dim3(256), 0,
                         stream, kvp + (long long)KLIN * DIM_, vt, KLIN, DIM_,
                         KVS, (long long)DIM_ * KLIN);
      // fused attention in-place on qc (QBLK=64, 256 threads, 2 blocks/CU)
      hipLaunchKernelGGL(attn_k, dim3(N_ / 64, HEADS, acb), dim3(256), 0,
                         stream, qc, kvp, vt, scale);
      // h += qc @ wo + wo_b  (8-phase 256x256, bf16 resid/out)
      hipLaunchKernelGGL((gemm8<1, 256, 256, 2>),
                         dim3(DIM_ / 256, (int)(acrows / 256), 1), dim3(512), 0,
                         stream, qc, wo_i, wo_b + i * DIM_,
                         (const float*)hc, (void*)hc, (int)acrows, DIM_, DIM_,
                         0LL, 0LL, 0LL, 0, 0LL);
    }

    // ---- FFN, (B_*N_)/frows chunks ----
    for (int r0 = 0; r0 < B_ * N_; r0 += frows) {
      short* hr = h + (long long)r0 * DIM_;
      hipLaunchKernelGGL(ln_k, dim3(frows / 4), dim3(256), 0, stream, hr,
                         ln2_s + i * DIM_, ln2_b + i * DIM_, zln);
      // ffnmid = gelu(zln @ w1 + b1)  (merged 2-phase 128x128, 2/CU)
      hipLaunchKernelGGL((gemm8m<1, 128, 128, 3>),
                         dim3(4 * DIM_ / 128, frows / 128, 1), dim3(512), 0,
                         stream, zln, w1_i, b1 + (long long)i * 4 * DIM_,
                         nullptr, (void*)ffnmid, frows, 4 * DIM_, DIM_, 0LL,
                         0LL, 0LL, 0, 0LL);
      // h += ffnmid @ w2 + b2  (merged 2-phase 128x128, bf16 resid/out)
      hipLaunchKernelGGL((gemm8m<1, 128, 128, 2>),
                         dim3(DIM_ / 128, frows / 128, 1), dim3(512), 0,
                         stream, ffnmid, w2_i, b2 + (long long)i * DIM_,
                         (const float*)hr, (void*)hr, frows, DIM_, 4 * DIM_,
                         0LL, 0LL, 0LL, 0, 0LL);
    }
  }

  hipLaunchKernelGGL(pool1_k, dim3(16, B_), dim3(256), 0, stream, h, partial);
  hipLaunchKernelGGL(pool2_k, dim3(B_), dim3(256), 0, stream, partial, pooled);
  hipLaunchKernelGGL(fc_k, dim3(1), dim3(64), 0, stream, pooled, fc_w, fc_b,
                     out);
}

// Round 12
// 1714.374 us; speedup vs baseline: 1.0889x; 1.0533x over previous
//
#include <hip/hip_runtime.h>
#include <math.h>

// ---------------- constants ----------------
#define B_    16
#define N_    2048
#define INDIM 64
#define DIM_  512
#define HEADS 8
#define DEPTH 4
#define KLIN  256
#define NCLS  2
#define DH    64
#define EPSF  1e-5f

typedef __attribute__((ext_vector_type(8))) short short8v;
typedef __attribute__((ext_vector_type(4))) short short4v;
typedef __attribute__((ext_vector_type(4))) float f32x4;

#define SBAR() __builtin_amdgcn_sched_barrier(0)

// fp32 -> bf16 round-to-nearest-even (finite inputs)
__device__ __forceinline__ short f2bf(float f) {
  unsigned u = __float_as_uint(f);
  u += 0x7FFFu + ((u >> 16) & 1u);
  return (short)(u >> 16);
}
// bf16 -> fp32
__device__ __forceinline__ float bf2f(short s) {
  return __uint_as_float((unsigned)(unsigned short)s << 16);
}

__device__ __forceinline__ float wave_sum(float v) {
  #pragma unroll
  for (int o = 32; o > 0; o >>= 1) v += __shfl_xor(v, o);
  return v;
}

// tanh-GELU via sigmoid identity (~7 VALU vs ~45+ libm tanhf)
__device__ __forceinline__ float gelu_tanh(float x) {
  float u = x * (1.5957691216057308f + 0.07135481627f * x * x);
  return x / (1.f + __expf(-u));
}

// async global->LDS, 16B per lane; LDS dest = wave-uniform base + lane*16
__device__ __forceinline__ void gl_lds16(const short* g, short* l) {
  __builtin_amdgcn_global_load_lds(
      (const __attribute__((address_space(1))) unsigned int*)g,
      (__attribute__((address_space(3))) unsigned int*)l, 16, 0, 0);
}

// ---------------- converts (once per launch) ----------------
__global__ __launch_bounds__(256) void tconv_k(const float* __restrict__ src,
                                               short* __restrict__ dst, int R,
                                               int C, long long sSrc,
                                               long long sDst) {
  __shared__ float tile[32][33];
  int c0 = blockIdx.x * 32, r0 = blockIdx.y * 32;
  src += (long long)blockIdx.z * sSrc;
  dst += (long long)blockIdx.z * sDst;
  int tx = threadIdx.x & 31, ty = threadIdx.x >> 5;
  #pragma unroll
  for (int rr = 0; rr < 4; ++rr)
    tile[ty + rr * 8][tx] = src[(long long)(r0 + ty + rr * 8) * C + c0 + tx];
  __syncthreads();
  #pragma unroll
  for (int rr = 0; rr < 4; ++rr) {
    int c = ty + rr * 8;
    dst[(long long)(c0 + c) * R + r0 + tx] = f2bf(tile[tx][c]);
  }
}

__global__ __launch_bounds__(256) void cconv_k(const float* __restrict__ src,
                                               short* __restrict__ dst,
                                               int n8) {
  int i = blockIdx.x * 256 + threadIdx.x;
  if (i < n8) {
    const float* s = src + (long long)i * 8;
    float4 a = *(const float4*)s, c = *(const float4*)(s + 4);
    short8v o = {f2bf(a.x), f2bf(a.y), f2bf(a.z), f2bf(a.w),
                 f2bf(c.x), f2bf(c.y), f2bf(c.z), f2bf(c.w)};
    *(short8v*)(dst + (long long)i * 8) = o;
  }
}

// ---------------- bf16 tile transpose: [R][C] -> [C][R], batched ----------
__global__ __launch_bounds__(256) void tpose_k(const short* __restrict__ src,
                                               short* __restrict__ dst, int R,
                                               int C, long long sSrc,
                                               long long sDst) {
  __shared__ __align__(16) short tile[64][72];
  int c0 = blockIdx.x * 64, r0 = blockIdx.y * 64;
  src += (long long)blockIdx.z * sSrc;
  dst += (long long)blockIdx.z * sDst;
  int t = threadIdx.x;
  #pragma unroll
  for (int rep = 0; rep < 2; ++rep) {
    int row = rep * 32 + (t >> 3), c8 = (t & 7) * 8;
    *(short8v*)&tile[row][c8] =
        *(const short8v*)(src + (long long)(r0 + row) * C + c0 + c8);
  }
  __syncthreads();
  #pragma unroll
  for (int rep = 0; rep < 2; ++rep) {
    int c = rep * 32 + (t >> 3), r8 = (t & 7) * 8;
    short8v o;
    #pragma unroll
    for (int j = 0; j < 8; ++j) o[j] = tile[r8 + j][c];
    *(short8v*)(dst + (long long)(c0 + c) * R + r0 + r8) = o;
  }
}

// ---------------- LayerNorm: bf16 in, bf16 out ----------------
__global__ __launch_bounds__(256) void ln_k(const short* __restrict__ h,
                                            const float* __restrict__ s,
                                            const float* __restrict__ b,
                                            short* __restrict__ z) {
  int lane = threadIdx.x & 63;
  long long row = ((long long)blockIdx.x << 2) + (threadIdx.x >> 6);
  const short* hr = h + row * DIM_ + lane * 8;
  short8v hv = *(const short8v*)hr;
  float x[8];
  #pragma unroll
  for (int i = 0; i < 8; ++i) x[i] = bf2f(hv[i]);
  float sum = 0.f;
  #pragma unroll
  for (int i = 0; i < 8; ++i) sum += x[i];
  sum = wave_sum(sum);
  float mu = sum * (1.f / DIM_);
  float d[8];
  #pragma unroll
  for (int i = 0; i < 8; ++i) d[i] = x[i] - mu;
  float vs = 0.f;
  #pragma unroll
  for (int i = 0; i < 8; ++i) vs += d[i] * d[i];
  vs = wave_sum(vs);
  float rstd = rsqrtf(vs * (1.f / DIM_) + EPSF);
  const float* sp = s + lane * 8;
  const float* bp = b + lane * 8;
  float4 s0 = *(const float4*)sp, s1 = *(const float4*)(sp + 4);
  float4 b0 = *(const float4*)bp, b1 = *(const float4*)(bp + 4);
  float o[8];
  o[0] = d[0] * rstd * s0.x + b0.x; o[1] = d[1] * rstd * s0.y + b0.y;
  o[2] = d[2] * rstd * s0.z + b0.z; o[3] = d[3] * rstd * s0.w + b0.w;
  o[4] = d[4] * rstd * s1.x + b1.x; o[5] = d[5] * rstd * s1.y + b1.y;
  o[6] = d[6] * rstd * s1.z + b1.z; o[7] = d[7] * rstd * s1.w + b1.w;
  short8v ov = {f2bf(o[0]), f2bf(o[1]), f2bf(o[2]), f2bf(o[3]),
                f2bf(o[4]), f2bf(o[5]), f2bf(o[6]), f2bf(o[7])};
  *(short8v*)(z + row * DIM_ + lane * 8) = ov;
}

// ---------------- fused LayerNorm + transpose: z AND zT in one pass ------
// 64 rows/block, 256 threads (4 waves x 16 row-iters). Same reduce order
// and single f2bf per element as ln_k -> z/zT bytes bit-identical to the
// ln_k + tpose_k pair it replaces. zT is per-batch [DIM][N_] (rows of one
// block never straddle a batch: 64 | N_).
__global__ __launch_bounds__(256) void lnt_k(const short* __restrict__ h,
                                             const float* __restrict__ s,
                                             const float* __restrict__ b,
                                             short* __restrict__ z,
                                             short* __restrict__ zT) {
  __shared__ __align__(16) short tile[64][514];  // +2 pad: stride 257 dwords
  int lane = threadIdx.x & 63, wid = threadIdx.x >> 6;
  long long row0 = (long long)blockIdx.x * 64;
  const float* sp = s + lane * 8;
  const float* bp = b + lane * 8;
  float4 s0 = *(const float4*)sp, s1 = *(const float4*)(sp + 4);
  float4 b0 = *(const float4*)bp, b1 = *(const float4*)(bp + 4);
  #pragma unroll 4
  for (int rr = 0; rr < 16; ++rr) {
    int rl = rr * 4 + wid;
    long long row = row0 + rl;
    short8v hv = *(const short8v*)(h + row * DIM_ + lane * 8);
    float x[8];
    #pragma unroll
    for (int i = 0; i < 8; ++i) x[i] = bf2f(hv[i]);
    float sum = 0.f;
    #pragma unroll
    for (int i = 0; i < 8; ++i) sum += x[i];
    sum = wave_sum(sum);
    float mu = sum * (1.f / DIM_);
    float d[8];
    #pragma unroll
    for (int i = 0; i < 8; ++i) d[i] = x[i] - mu;
    float vs = 0.f;
    #pragma unroll
    for (int i = 0; i < 8; ++i) vs += d[i] * d[i];
    vs = wave_sum(vs);
    float rstd = rsqrtf(vs * (1.f / DIM_) + EPSF);
    float o[8];
    o[0] = d[0] * rstd * s0.x + b0.x; o[1] = d[1] * rstd * s0.y + b0.y;
    o[2] = d[2] * rstd * s0.z + b0.z; o[3] = d[3] * rstd * s0.w + b0.w;
    o[4] = d[4] * rstd * s1.x + b1.x; o[5] = d[5] * rstd * s1.y + b1.y;
    o[6] = d[6] * rstd * s1.z + b1.z; o[7] = d[7] * rstd * s1.w + b1.w;
    short8v ov = {f2bf(o[0]), f2bf(o[1]), f2bf(o[2]), f2bf(o[3]),
                  f2bf(o[4]), f2bf(o[5]), f2bf(o[6]), f2bf(o[7])};
    *(short8v*)(z + row * DIM_ + lane * 8) = ov;
    *(short8v*)&tile[rl][lane * 8] = ov;
  }
  __syncthreads();
  // transposed write: zT[bb][d][n0 + j]
  long long bb = row0 / N_;
  int n0 = (int)(row0 % N_);
  short* zb = zT + bb * (long long)DIM_ * N_ + n0;
  int dg = threadIdx.x >> 3;        // 0..31: d-row group
  int jj = (threadIdx.x & 7) * 8;   // 0..56: n-offset
  #pragma unroll 4
  for (int it = 0; it < 16; ++it) {
    int d = it * 32 + dg;
    short8v o;
    #pragma unroll
    for (int j = 0; j < 8; ++j) o[j] = tile[jj + j][d];
    *(short8v*)(zb + (long long)d * N_ + jj) = o;
  }
}

// ---------------- bf16 MFMA GEMM, 2-phase pipeline (small shapes) --------
// epi: 0 none; 1 +bias; 2 +bias+resid[(m%resMod)*ldc+n] (fp32); 3 gelu(+bias)
template <int OUTBF, int BM, int BN>
__global__ __launch_bounds__(256) void gemm_bf(
    const short* __restrict__ A, const short* __restrict__ Bsrc,
    const float* __restrict__ bias, const float* __restrict__ resid,
    void* __restrict__ Cv, int M, int N, int K, int lda, int ldb, int ldc,
    long long sAb, long long sBb, long long sCb, int dualThresh,
    long long dualOff, int epi, int resMod) {
  constexpr int MT = BM / 32;   // frag rows per wave
  constexpr int NT = BN / 32;   // frag cols per wave
  constexpr int NLD = BM / 32 + BN / 32;  // global_load_lds per thread / tile
  int zz = blockIdx.z;
  A += (long long)zz * sAb;
  Bsrc += (long long)zz * sBb;
  int bm = blockIdx.y * BM, bn = blockIdx.x * BN;
  if (dualThresh && bm >= dualThresh) Bsrc += dualOff;
  int t = threadIdx.x;
  __shared__ __align__(16) short Alds[2][BM * 64];
  __shared__ __align__(16) short Blds[2][BN * 64];
  int lane = t & 63, wid = t >> 6;
  int lr = lane & 15, q = lane >> 4;
  int wm = (wid >> 1) * (BM / 2), wn = (wid & 1) * (BN / 2);
  int rl = lane >> 3;          // row within 8-row group
  int cs = (lane & 7) ^ rl;    // swizzled source chunk
  f32x4 acc[MT][NT] = {};

  // stage one BK=64 tile (A + B) into LDS buffer `buf`
  auto stage = [&](int buf, int k0) {
    #pragma unroll
    for (int i = 0; i < BM / 32; ++i) {
      int rb = i * 32 + wid * 8;
      gl_lds16(A + (long long)(bm + rb + rl) * lda + k0 + cs * 8,
               &Alds[buf][rb * 64]);
    }
    #pragma unroll
    for (int i = 0; i < BN / 32; ++i) {
      int rb = i * 32 + wid * 8;
      gl_lds16(Bsrc + (long long)(bn + rb + rl) * ldb + k0 + cs * 8,
               &Blds[buf][rb * 64]);
    }
  };

  stage(0, 0);  // prologue: tile 0 in flight
  int cur = 0;
  for (int k0 = 0; k0 < K; k0 += 64, cur ^= 1) {
    if (k0 + 64 < K) {
      stage(cur ^ 1, k0 + 64);  // prefetch next tile (overlaps MFMA below)
      SBAR();  // pin issue above the counted wait
      asm volatile("s_waitcnt vmcnt(%0)" ::"n"(NLD) : "memory");  // tile k0 done
    } else {
      SBAR();
      asm volatile("s_waitcnt vmcnt(0)" ::: "memory");
    }
    __builtin_amdgcn_s_barrier();        // everyone's tile-k0 loads landed
    SBAR();                              // keep ds_reads below the barrier
    #pragma unroll
    for (int kk2 = 0; kk2 < 2; ++kk2) {
      short8v af[MT], bfr[NT];
      #pragma unroll
      for (int mi = 0; mi < MT; ++mi)
        af[mi] = *(const short8v*)&Alds[cur][(wm + mi * 16 + lr) * 64 +
                                             (((kk2 << 2) | q) ^ (lr & 7)) * 8];
      #pragma unroll
      for (int ni = 0; ni < NT; ++ni)
        bfr[ni] = *(const short8v*)&Blds[cur][(wn + ni * 16 + lr) * 64 +
                                              (((kk2 << 2) | q) ^ (lr & 7)) * 8];
      #pragma unroll
      for (int mi = 0; mi < MT; ++mi)
        #pragma unroll
        for (int ni = 0; ni < NT; ++ni)
          acc[mi][ni] = __builtin_amdgcn_mfma_f32_16x16x32_bf16(
              bfr[ni], af[mi], acc[mi][ni], 0, 0, 0);  // swapped: cols in regs
    }
    SBAR();                              // reads of buf[cur] complete here
    __builtin_amdgcn_s_barrier();        // before next iter overwrites it
  }

  #pragma unroll
  for (int mi = 0; mi < MT; ++mi) {
    int m = bm + wm + mi * 16 + lr;
    int rm = (epi == 2 && resMod) ? (m % resMod) : m;
    #pragma unroll
    for (int ni = 0; ni < NT; ++ni) {
      int nb = bn + wn + ni * 16 + q * 4;
      f32x4 v = acc[mi][ni];
      if (epi >= 1) {
        float4 bb = *(const float4*)(bias + nb);
        v[0] += bb.x; v[1] += bb.y; v[2] += bb.z; v[3] += bb.w;
      }
      if (epi == 2) {
        float4 rr = *(const float4*)(resid + (long long)rm * ldc + nb);
        v[0] += rr.x; v[1] += rr.y; v[2] += rr.z; v[3] += rr.w;
      } else if (epi == 3) {
        v[0] = gelu_tanh(v[0]); v[1] = gelu_tanh(v[1]);
        v[2] = gelu_tanh(v[2]); v[3] = gelu_tanh(v[3]);
      }
      long long base = (long long)zz * sCb + (long long)m * ldc + nb;
      if (OUTBF) {
        short4v o = {f2bf(v[0]), f2bf(v[1]), f2bf(v[2]), f2bf(v[3])};
        *(short4v*)((short*)Cv + base) = o;
      } else {
        *(float4*)((float*)Cv + base) = make_float4(v[0], v[1], v[2], v[3]);
      }
    }
  }
}

// ---------------- 8-phase bf16 MFMA GEMM (big shapes, batched) ------------
// R8 best-timed config: B-lo+B-hi(t+1) at P3; counted vmcnt(LA); T1 swizzle.
// EPI: 0 none; 2 bias + BF16 resid; 3 bias+gelu.
template <int OUTBF, int BM, int BN, int EPI>
__global__ __launch_bounds__(512, 2) void gemm8(
    const short* __restrict__ A, const short* __restrict__ Bt,
    const float* __restrict__ bias, const float* __restrict__ resid,
    void* __restrict__ Cv, int M, int N, int K, long long sAb, long long sBb,
    long long sCb, int dualThresh, long long dualOff) {
  constexpr int MH = BM / 64;
  constexpr int WCOL = BN / 4;
  constexpr int NT = WCOL / 16;
  constexpr int NTH = NT / 2;
  constexpr int LB = BN / 128;
  constexpr int LA = BM / 128;
  __shared__ __align__(16) short Alds[2][BM * 64];
  __shared__ __align__(16) short Blds[2][BN * 64];
  const int tid = threadIdx.x;
  const int lane = tid & 63, wid = tid >> 6;
  const int lr = lane & 15, q = lane >> 4;
  const int wm = (wid >> 2) * (BM / 2), wn = (wid & 3) * WCOL;
  const int rl = lane >> 3, cs = (lane & 7) ^ rl;
  const int zz = blockIdx.z;
  A += (long long)zz * sAb;
  Bt += (long long)zz * sBb;
  const int nwg = gridDim.x * gridDim.y;
  int bid = blockIdx.y * gridDim.x + blockIdx.x;
  const int nx8 = nwg >> 3, r8 = nwg & 7, xcd = bid & 7, loc = bid >> 3;
  int swz = (xcd < r8 ? xcd * (nx8 + 1) : r8 * (nx8 + 1) + (xcd - r8) * nx8)
            + loc;
  const int bm = (swz / gridDim.x) * BM, bn = (swz % gridDim.x) * BN;
  if (dualThresh && bm >= dualThresh) Bt += dualOff;
  const short* Ag = A + (long long)bm * K + cs * 8;
  const short* Bg = Bt + (long long)bn * K + cs * 8;
  f32x4 acc[2 * MH][NT] = {};

  auto stageA = [&](int slot, int h, int k0) {
    #pragma unroll
    for (int j = 0; j < LA; ++j) {
      int rb = h * (BM / 2) + j * 64 + wid * 8;
      gl_lds16(Ag + (long long)(rb + rl) * K + k0, &Alds[slot][rb * 64]);
    }
  };
  auto stageB = [&](int slot, int h, int k0) {
    #pragma unroll
    for (int j = 0; j < LB; ++j) {
      int rb = h * (BN / 2) + j * 64 + wid * 8;
      gl_lds16(Bg + (long long)(rb + rl) * K + k0, &Blds[slot][rb * 64]);
    }
  };
  auto rd = [&](const short* Ls, int row, int kk) -> short8v {
    return *(const short8v*)&Ls[row * 64 + ((((kk << 2) | q) ^ (lr & 7)) << 3)];
  };
  auto mfma4 = [&](short8v (&af)[MH][2], short8v (&bf)[NTH][2], int mo,
                   int no) {
    #pragma unroll
    for (int mi = 0; mi < MH; ++mi)
      #pragma unroll
      for (int ni = 0; ni < NTH; ++ni)
        #pragma unroll
        for (int kk = 0; kk < 2; ++kk)
          acc[mo + mi][no + ni] = __builtin_amdgcn_mfma_f32_16x16x32_bf16(
              bf[ni][kk], af[mi][kk], acc[mo + mi][no + ni], 0, 0, 0);
  };

  const int T = K >> 6;
  stageA(0, 0, 0); stageA(0, 1, 0); stageB(0, 0, 0); stageB(0, 1, 0);
  if (T > 1) {
    stageA(1, 0, 64);
    SBAR();
    asm volatile("s_waitcnt vmcnt(%0)" ::"n"(LA) : "memory");
  } else {
    SBAR();
    asm volatile("s_waitcnt vmcnt(0)" ::: "memory");
  }
  __builtin_amdgcn_s_barrier();

  for (int tt = 0; tt < T; ++tt) {
    const int s = tt & 1, ns = s ^ 1;
    const int kn = (tt + 1) << 6, kn2 = (tt + 2) << 6;
    const short* Als = Alds[s];
    const short* Bls = Blds[s];
    short8v af0[MH][2], af1[MH][2], bf0[NTH][2], bf1[NTH][2];
    // ---- P1: quadrant (row-lo x col-lo); stage A-hi(t+1) ----
    SBAR();
    #pragma unroll
    for (int mi = 0; mi < MH; ++mi)
      #pragma unroll
      for (int kk = 0; kk < 2; ++kk)
        af0[mi][kk] = rd(Als, wm + mi * 16 + lr, kk);
    #pragma unroll
    for (int ni = 0; ni < NTH; ++ni)
      #pragma unroll
      for (int kk = 0; kk < 2; ++kk)
        bf0[ni][kk] = rd(Bls, wn + ni * 16 + lr, kk);
    if (tt + 1 < T) stageA(ns, 1, kn);
    if (BN == 256) asm volatile("s_waitcnt lgkmcnt(8)" ::: "memory");
    SBAR();
    __builtin_amdgcn_s_barrier();
    asm volatile("s_waitcnt lgkmcnt(0)" ::: "memory");
    SBAR();
    __builtin_amdgcn_s_setprio(1);
    mfma4(af0, bf0, 0, 0);
    __builtin_amdgcn_s_setprio(0);
    SBAR();
    __builtin_amdgcn_s_barrier();
    // ---- P2: (row-lo x col-hi) ----
    SBAR();
    #pragma unroll
    for (int ni = 0; ni < NTH; ++ni)
      #pragma unroll
      for (int kk = 0; kk < 2; ++kk)
        bf1[ni][kk] = rd(Bls, wn + (NTH + ni) * 16 + lr, kk);
    SBAR();
    __builtin_amdgcn_s_barrier();
    asm volatile("s_waitcnt lgkmcnt(0)" ::: "memory");
    SBAR();
    __builtin_amdgcn_s_setprio(1);
    mfma4(af0, bf1, 0, NTH);
    __builtin_amdgcn_s_setprio(0);
    SBAR();
    __builtin_amdgcn_s_barrier();
    // ---- P3: (row-hi x col-lo); stage B-lo(t+1) + B-hi(t+1) ----
    SBAR();
    #pragma unroll
    for (int mi = 0; mi < MH; ++mi)
      #pragma unroll
      for (int kk = 0; kk < 2; ++kk)
        af1[mi][kk] = rd(Als, wm + MH * 16 + mi * 16 + lr, kk);
    if (tt + 1 < T) { stageB(ns, 0, kn); stageB(ns, 1, kn); }
    SBAR();
    __builtin_amdgcn_s_barrier();
    asm volatile("s_waitcnt lgkmcnt(0)" ::: "memory");
    SBAR();
    __builtin_amdgcn_s_setprio(1);
    mfma4(af1, bf0, MH, 0);
    __builtin_amdgcn_s_setprio(0);
    SBAR();
    __builtin_amdgcn_s_barrier();
    // ---- P4: (row-hi x col-hi); stage A-lo(t+2); counted wait ----
    SBAR();
    if (tt + 2 < T) stageA(s, 0, kn2);
    SBAR();
    __builtin_amdgcn_s_barrier();
    __builtin_amdgcn_s_setprio(1);
    mfma4(af1, bf1, MH, NTH);
    __builtin_amdgcn_s_setprio(0);
    if (tt + 2 < T) {
      SBAR();
      asm volatile("s_waitcnt vmcnt(%0)" ::"n"(LA) : "memory");  // t+1 landed
    } else if (tt + 1 < T) {
      SBAR();
      asm volatile("s_waitcnt vmcnt(0)" ::: "memory");  // final tile landed
    }
    SBAR();
    __builtin_amdgcn_s_barrier();
  }

  #pragma unroll
  for (int mi = 0; mi < 2 * MH; ++mi) {
    int m = bm + wm + mi * 16 + lr;
    #pragma unroll
    for (int nj = 0; nj < NT; ++nj) {
      int nb = bn + wn + nj * 16 + q * 4;
      f32x4 v = acc[mi][nj];
      if (EPI >= 1) {
        float4 bb = *(const float4*)(bias + nb);
        v[0] += bb.x; v[1] += bb.y; v[2] += bb.z; v[3] += bb.w;
      }
      if (EPI == 2) {
        const short* rp = (const short*)resid;
        short4v rr = *(const short4v*)(rp + (long long)m * N + nb);
        v[0] += bf2f(rr[0]); v[1] += bf2f(rr[1]);
        v[2] += bf2f(rr[2]); v[3] += bf2f(rr[3]);
      } else if (EPI == 3) {
        v[0] = gelu_tanh(v[0]); v[1] = gelu_tanh(v[1]);
        v[2] = gelu_tanh(v[2]); v[3] = gelu_tanh(v[3]);
      }
      long long base = (long long)zz * sCb + (long long)m * N + nb;
      if (OUTBF) {
        short4v o = {f2bf(v[0]), f2bf(v[1]), f2bf(v[2]), f2bf(v[3])};
        *(short4v*)((short*)Cv + base) = o;
      } else {
        *(float4*)((float*)Cv + base) = make_float4(v[0], v[1], v[2], v[3]);
      }
    }
  }
}

// ---------------- merged 2-phase variant of gemm8 (for small tiles) -------
// R8 config (best timed): ALL of tile t+1 staged in P1; A-lo(t+2) in P2.
// EPI==2 = bias + BF16 resid (h stream).
template <int OUTBF, int BM, int BN, int EPI>
__global__ __launch_bounds__(512, 2) void gemm8m(
    const short* __restrict__ A, const short* __restrict__ Bt,
    const float* __restrict__ bias, const float* __restrict__ resid,
    void* __restrict__ Cv, int M, int N, int K, long long sAb, long long sBb,
    long long sCb, int dualThresh, long long dualOff) {
  constexpr int MH = BM / 64;
  constexpr int WCOL = BN / 4;
  constexpr int NT = WCOL / 16;
  constexpr int NTH = NT / 2;
  constexpr int LB = BN / 128;
  constexpr int LA = BM / 128;
  __shared__ __align__(16) short Alds[2][BM * 64];
  __shared__ __align__(16) short Blds[2][BN * 64];
  const int tid = threadIdx.x;
  const int lane = tid & 63, wid = tid >> 6;
  const int lr = lane & 15, q = lane >> 4;
  const int wm = (wid >> 2) * (BM / 2), wn = (wid & 3) * WCOL;
  const int rl = lane >> 3, cs = (lane & 7) ^ rl;
  const int zz = blockIdx.z;
  A += (long long)zz * sAb;
  Bt += (long long)zz * sBb;
  const int nwg = gridDim.x * gridDim.y;
  int bid = blockIdx.y * gridDim.x + blockIdx.x;
  const int nx8 = nwg >> 3, r8 = nwg & 7, xcd = bid & 7, loc = bid >> 3;
  int swz = (xcd < r8 ? xcd * (nx8 + 1) : r8 * (nx8 + 1) + (xcd - r8) * nx8)
            + loc;
  const int bm = (swz / gridDim.x) * BM, bn = (swz % gridDim.x) * BN;
  if (dualThresh && bm >= dualThresh) Bt += dualOff;
  const short* Ag = A + (long long)bm * K + cs * 8;
  const short* Bg = Bt + (long long)bn * K + cs * 8;
  f32x4 acc[2 * MH][NT] = {};

  auto stageA = [&](int slot, int h, int k0) {
    #pragma unroll
    for (int j = 0; j < LA; ++j) {
      int rb = h * (BM / 2) + j * 64 + wid * 8;
      gl_lds16(Ag + (long long)(rb + rl) * K + k0, &Alds[slot][rb * 64]);
    }
  };
  auto stageB = [&](int slot, int h, int k0) {
    #pragma unroll
    for (int j = 0; j < LB; ++j) {
      int rb = h * (BN / 2) + j * 64 + wid * 8;
      gl_lds16(Bg + (long long)(rb + rl) * K + k0, &Blds[slot][rb * 64]);
    }
  };
  auto rd = [&](const short* Ls, int row, int kk) -> short8v {
    return *(const short8v*)&Ls[row * 64 + ((((kk << 2) | q) ^ (lr & 7)) << 3)];
  };
  auto mfma4 = [&](short8v (&af)[MH][2], short8v (&bf)[NTH][2], int mo,
                   int no) {
    #pragma unroll
    for (int mi = 0; mi < MH; ++mi)
      #pragma unroll
      for (int ni = 0; ni < NTH; ++ni)
        #pragma unroll
        for (int kk = 0; kk < 2; ++kk)
          acc[mo + mi][no + ni] = __builtin_amdgcn_mfma_f32_16x16x32_bf16(
              bf[ni][kk], af[mi][kk], acc[mo + mi][no + ni], 0, 0, 0);
  };

  const int T = K >> 6;
  stageA(0, 0, 0); stageA(0, 1, 0); stageB(0, 0, 0); stageB(0, 1, 0);
  if (T > 1) {
    stageA(1, 0, 64);
    SBAR();
    asm volatile("s_waitcnt vmcnt(%0)" ::"n"(LA) : "memory");
  } else {
    SBAR();
    asm volatile("s_waitcnt vmcnt(0)" ::: "memory");
  }
  __builtin_amdgcn_s_barrier();

  for (int tt = 0; tt < T; ++tt) {
    const int s = tt & 1, ns = s ^ 1;
    const int kn = (tt + 1) << 6, kn2 = (tt + 2) << 6;
    const short* Als = Alds[s];
    const short* Bls = Blds[s];
    short8v af0[MH][2], af1[MH][2], bf0[NTH][2], bf1[NTH][2];
    // ---- P1 (merged): row-lo x all cols; stage ALL of tile t+1 ----
    SBAR();
    #pragma unroll
    for (int mi = 0; mi < MH; ++mi)
      #pragma unroll
      for (int kk = 0; kk < 2; ++kk)
        af0[mi][kk] = rd(Als, wm + mi * 16 + lr, kk);
    #pragma unroll
    for (int ni = 0; ni < NTH; ++ni)
      #pragma unroll
      for (int kk = 0; kk < 2; ++kk) {
        bf0[ni][kk] = rd(Bls, wn + ni * 16 + lr, kk);
        bf1[ni][kk] = rd(Bls, wn + (NTH + ni) * 16 + lr, kk);
      }
    if (tt + 1 < T) {
      stageA(ns, 1, kn);
      stageB(ns, 0, kn);
      stageB(ns, 1, kn);
    }
    SBAR();
    __builtin_amdgcn_s_barrier();
    asm volatile("s_waitcnt lgkmcnt(0)" ::: "memory");
    SBAR();
    __builtin_amdgcn_s_setprio(1);
    mfma4(af0, bf0, 0, 0);
    mfma4(af0, bf1, 0, NTH);
    __builtin_amdgcn_s_setprio(0);
    SBAR();
    __builtin_amdgcn_s_barrier();
    // ---- P2 (merged): row-hi x all cols; stage A-lo(t+2) ----
    SBAR();
    #pragma unroll
    for (int mi = 0; mi < MH; ++mi)
      #pragma unroll
      for (int kk = 0; kk < 2; ++kk)
        af1[mi][kk] = rd(Als, wm + MH * 16 + mi * 16 + lr, kk);
    if (tt + 2 < T) stageA(s, 0, kn2);
    SBAR();
    __builtin_amdgcn_s_barrier();
    asm volatile("s_waitcnt lgkmcnt(0)" ::: "memory");
    SBAR();
    __builtin_amdgcn_s_setprio(1);
    mfma4(af1, bf0, MH, 0);
    mfma4(af1, bf1, MH, NTH);
    __builtin_amdgcn_s_setprio(0);
    if (tt + 2 < T) {
      SBAR();
      asm volatile("s_waitcnt vmcnt(%0)" ::"n"(LA) : "memory");  // t+1 landed
    } else if (tt + 1 < T) {
      SBAR();
      asm volatile("s_waitcnt vmcnt(0)" ::: "memory");
    }
    SBAR();
    __builtin_amdgcn_s_barrier();
  }

  #pragma unroll
  for (int mi = 0; mi < 2 * MH; ++mi) {
    int m = bm + wm + mi * 16 + lr;
    #pragma unroll
    for (int nj = 0; nj < NT; ++nj) {
      int nb = bn + wn + nj * 16 + q * 4;
      f32x4 v = acc[mi][nj];
      if (EPI >= 1) {
        float4 bb = *(const float4*)(bias + nb);
        v[0] += bb.x; v[1] += bb.y; v[2] += bb.z; v[3] += bb.w;
      }
      if (EPI == 2) {
        const short* rp = (const short*)resid;
        short4v rr = *(const short4v*)(rp + (long long)m * N + nb);
        v[0] += bf2f(rr[0]); v[1] += bf2f(rr[1]);
        v[2] += bf2f(rr[2]); v[3] += bf2f(rr[3]);
      } else if (EPI == 3) {
        v[0] = gelu_tanh(v[0]); v[1] = gelu_tanh(v[1]);
        v[2] = gelu_tanh(v[2]); v[3] = gelu_tanh(v[3]);
      }
      long long base = (long long)zz * sCb + (long long)m * N + nb;
      if (OUTBF) {
        short4v o = {f2bf(v[0]), f2bf(v[1]), f2bf(v[2]), f2bf(v[3])};
        *(short4v*)((short*)Cv + base) = o;
      } else {
        *(float4*)((float*)Cv + base) = make_float4(v[0], v[1], v[2], v[3]);
      }
    }
  }
}

// ---------------- fused Linformer attention, bf16 MFMA ----------------
// QBLK=64, 256 threads, LDS 78KB -> 2 blocks/CU (proven R3 config).
__global__ __launch_bounds__(256) void attn_k(short* __restrict__ qc,
                                              const short* __restrict__ kvp,
                                              const short* __restrict__ vt,
                                              float scale) {
  int n0 = blockIdx.x * 64, hh = blockIdx.y, b = blockIdx.z;
  int t = threadIdx.x;
  int lane = t & 63, w = t >> 6;
  int lr = lane & 15, qd = lane >> 4;

  __shared__ __align__(16) short Qlds[64][72];
  __shared__ __align__(16) short Kbuf[256 * 72];  // K, then aliased as P
  __shared__ __align__(16) short Vt[64][264];
  auto Klds = (short(*)[72])Kbuf;
  auto Plds = (short(*)[264])Kbuf;

  short* qptr = qc + (long long)b * N_ * DIM_ + hh * DH;
  const short* kptr = kvp + (long long)b * 2 * KLIN * DIM_ + hh * DH;
  const short* vtp = vt + (long long)b * DIM_ * KLIN + (long long)hh * DH * KLIN;

  #pragma unroll
  for (int rep = 0; rep < 2; ++rep) {
    int L = rep * 256 + t, row = L >> 3, c8 = (L & 7) << 3;
    *(short8v*)&Qlds[row][c8] =
        *(const short8v*)(qptr + (long long)(n0 + row) * DIM_ + c8);
  }
  #pragma unroll
  for (int rep = 0; rep < 8; ++rep) {
    int L = rep * 256 + t, row = L >> 3, c8 = (L & 7) << 3;
    *(short8v*)&Klds[row][c8] =
        *(const short8v*)(kptr + (long long)row * DIM_ + c8);
  }
  // V^T rows (dh-major, 256 k-cols each): coalesced, conflict-free staging
  #pragma unroll
  for (int rep = 0; rep < 8; ++rep) {
    int L = rep * 256 + t, row = L >> 5, c8 = (L & 31) << 3;
    *(short8v*)&Vt[row][c8] =
        *(const short8v*)(vtp + (long long)row * KLIN + c8);
  }
  __syncthreads();

  short8v qa0 = *(const short8v*)&Qlds[16 * w + lr][qd * 8];
  short8v qa1 = *(const short8v*)&Qlds[16 * w + lr][32 + qd * 8];
  f32x4 sacc[16];
  #pragma unroll
  for (int nt = 0; nt < 16; ++nt) {
    short8v b0 = *(const short8v*)&Klds[nt * 16 + lr][qd * 8];
    short8v b1 = *(const short8v*)&Klds[nt * 16 + lr][32 + qd * 8];
    f32x4 acc = {};
    acc = __builtin_amdgcn_mfma_f32_16x16x32_bf16(b0, qa0, acc, 0, 0, 0);
    acc = __builtin_amdgcn_mfma_f32_16x16x32_bf16(b1, qa1, acc, 0, 0, 0);
    sacc[nt] = acc;
  }

  // softmax over the lane-local row slice (64 vals) + 2-shfl qd reduction.
  float mx = -1e30f;
  #pragma unroll
  for (int nt = 0; nt < 16; ++nt)
    #pragma unroll
    for (int r = 0; r < 4; ++r) mx = fmaxf(mx, sacc[nt][r]);
  mx = fmaxf(mx, __shfl_xor(mx, 16));
  mx = fmaxf(mx, __shfl_xor(mx, 32));
  float rs = 0.f;
  #pragma unroll
  for (int nt = 0; nt < 16; ++nt)
    #pragma unroll
    for (int r = 0; r < 4; ++r) {
      float e = __expf((sacc[nt][r] - mx) * scale);
      sacc[nt][r] = e;
      rs += e;
    }
  rs += __shfl_xor(rs, 16);
  rs += __shfl_xor(rs, 32);
  float inv = 1.f / rs;

  __syncthreads();  // Klds reads done; reuse as Plds
  #pragma unroll
  for (int nt = 0; nt < 16; ++nt) {
    short4v p = {f2bf(sacc[nt][0] * inv), f2bf(sacc[nt][1] * inv),
                 f2bf(sacc[nt][2] * inv), f2bf(sacc[nt][3] * inv)};
    *(short4v*)&Plds[16 * w + lr][nt * 16 + qd * 4] = p;
  }
  __syncthreads();

  f32x4 out[4] = {};
  #pragma unroll
  for (int k0 = 0; k0 < 8; ++k0) {
    short8v ap = *(const short8v*)&Plds[16 * w + lr][k0 * 32 + qd * 8];
    #pragma unroll
    for (int n2 = 0; n2 < 4; ++n2) {
      short8v bv = *(const short8v*)&Vt[n2 * 16 + lr][k0 * 32 + qd * 8];
      out[n2] =
          __builtin_amdgcn_mfma_f32_16x16x32_bf16(bv, ap, out[n2], 0, 0, 0);
    }
  }

  long long rowoff = (long long)(n0 + 16 * w + lr) * DIM_;
  #pragma unroll
  for (int n2 = 0; n2 < 4; ++n2) {
    short4v o = {f2bf(out[n2][0]), f2bf(out[n2][1]), f2bf(out[n2][2]),
                 f2bf(out[n2][3])};
    *(short4v*)(qptr + rowoff + n2 * 16 + qd * 4) = o;
  }
}

// ---------------- two-stage mean pool (bf16 h) ----------------
__global__ __launch_bounds__(256) void pool1_k(const short* __restrict__ h,
                                               float* __restrict__ partial) {
  int stripe = blockIdx.x, b = blockIdx.y;
  int c8 = (threadIdx.x & 63) * 8, grp = threadIdx.x >> 6;  // 4 row-groups
  const short* base =
      h + ((long long)b * N_ + stripe * 128 + grp * 32) * DIM_ + c8;
  float acc[8] = {};
  for (int r = 0; r < 32; ++r) {
    short8v v = *(const short8v*)(base + (long long)r * DIM_);
    #pragma unroll
    for (int i = 0; i < 8; ++i) acc[i] += bf2f(v[i]);
  }
  __shared__ float red[3][512];
  if (grp) {
    *(float4*)&red[grp - 1][c8] = make_float4(acc[0], acc[1], acc[2], acc[3]);
    *(float4*)&red[grp - 1][c8 + 4] =
        make_float4(acc[4], acc[5], acc[6], acc[7]);
  }
  __syncthreads();
  if (grp == 0) {
    float o[8];
    #pragma unroll
    for (int i = 0; i < 8; ++i)
      o[i] = acc[i] + red[0][c8 + i] + red[1][c8 + i] + red[2][c8 + i];
    float* pp = &partial[((long long)b * 16 + stripe) * DIM_ + c8];
    *(float4*)pp = make_float4(o[0], o[1], o[2], o[3]);
    *(float4*)(pp + 4) = make_float4(o[4], o[5], o[6], o[7]);
  }
}
__global__ __launch_bounds__(256) void pool2_k(const float* __restrict__ partial,
                                               float* __restrict__ pooled) {
  int b = blockIdx.x;
  for (int c = threadIdx.x; c < DIM_; c += 256) {
    float s = 0.f;
    for (int k = 0; k < 16; ++k) s += partial[((long long)b * 16 + k) * DIM_ + c];
    pooled[b * DIM_ + c] = s * (1.f / N_);
  }
}

// ---------------- final FC [16,512]@[512,2] ----------------
__global__ __launch_bounds__(64) void fc_k(const float* __restrict__ pooled,
                                           const float* __restrict__ fc_w,
                                           const float* __restrict__ fc_b,
                                           float* __restrict__ out) {
  int t = threadIdx.x;
  if (t < B_ * NCLS) {
    int b = t >> 1, c = t & 1;
    float s = fc_b[c];
    for (int d = 0; d < DIM_; ++d)
      s += pooled[b * DIM_ + d] * fc_w[d * NCLS + c];
    out[t] = s;
  }
}

extern "C" void kernel_launch(void* const* d_in, const int* in_sizes, int n_in,
                              void* d_out, int out_size, void* d_ws,
                              size_t ws_size, hipStream_t stream) {
  const float* x     = (const float*)d_in[0];
  const float* emb_w = (const float*)d_in[1];
  const float* emb_b = (const float*)d_in[2];
  const float* pos   = (const float*)d_in[3];
  const float* ln1_s = (const float*)d_in[4];
  const float* ln1_b = (const float*)d_in[5];
  const float* wq    = (const float*)d_in[6];
  const float* wk    = (const float*)d_in[7];
  const float* wv    = (const float*)d_in[8];
  const float* pk    = (const float*)d_in[9];
  const float* pv    = (const float*)d_in[10];
  const float* wo    = (const float*)d_in[11];
  const float* wo_b  = (const float*)d_in[12];
  const float* ln2_s = (const float*)d_in[13];
  const float* ln2_b = (const float*)d_in[14];
  const float* w1    = (const float*)d_in[15];
  const float* b1    = (const float*)d_in[16];
  const float* w2    = (const float*)d_in[17];
  const float* b2    = (const float*)d_in[18];
  const float* fc_w  = (const float*)d_in[19];
  const float* fc_b  = (const float*)d_in[20];
  float* out = (float*)d_out;

  const bool big = ws_size >= (size_t)230 * 1024 * 1024;
  const int acb = big ? 16 : 8;          // batches per attention chunk
  const long long acrows = (long long)acb * N_;
  const int frows = big ? 16384 : 8192;  // rows per FFN chunk

  char* P = (char*)d_ws;
  short* h = (short*)P;            P += (long long)B_ * N_ * DIM_ * 2;  // 33.5MB bf16
  short* zc = (short*)P;           P += acrows * DIM_ * 2;
  short* qc = (short*)P;           P += acrows * DIM_ * 2;
  short* ffnmid = zc;              // frows*4*DIM == 2*acrows*DIM exactly
  short* zcT = (short*)P;          P += acrows * DIM_ * 2;   // also zln (FFN)
  short* zln = zcT;
  short* zp = (short*)P;           P += (long long)acb * 2 * KLIN * DIM_ * 2;
  short* kvp = (short*)P;          P += (long long)acb * 2 * KLIN * DIM_ * 2;
  short* vt = zp;                  // V^T scratch: zp is dead after kvp GEMM
  short* wq_t  = (short*)P;  P += (long long)DEPTH * DIM_ * DIM_ * 2;
  short* wkv_t = (short*)P;  P += (long long)DEPTH * 2 * DIM_ * DIM_ * 2;
  short* wo_t  = (short*)P;  P += (long long)DEPTH * DIM_ * DIM_ * 2;
  short* w1_t  = (short*)P;  P += (long long)DEPTH * 4 * DIM_ * DIM_ * 2;
  short* w2_t  = (short*)P;  P += (long long)DEPTH * 4 * DIM_ * DIM_ * 2;
  short* pkv_t = (short*)P;  P += (long long)DEPTH * 2 * KLIN * N_ * 2;
  short* emb_wt = (short*)P; P += (long long)DIM_ * INDIM * 2;
  short* x_bf  = (short*)P;  P += (long long)B_ * N_ * INDIM * 2;
  float* partial = (float*)P; P += (long long)B_ * 16 * DIM_ * 4;
  float* pooled  = (float*)P;

  const float scale = 0.125f;
  const long long WQS = (long long)DIM_ * DIM_;        // 262144
  const long long KVS = (long long)2 * KLIN * DIM_;    // 262144

  // ---- converts ----
  auto tconv = [&](const float* s, short* d, int R, int C, long long ss,
                   long long sd, int b) {
    hipLaunchKernelGGL(tconv_k, dim3(C / 32, R / 32, b), dim3(256), 0, stream,
                       s, d, R, C, ss, sd);
  };
  tconv(wq, wq_t, DIM_, DIM_, WQS, WQS, DEPTH);
  tconv(wk, wkv_t, DIM_, DIM_, WQS, 2 * WQS, DEPTH);
  tconv(wv, wkv_t + WQS, DIM_, DIM_, WQS, 2 * WQS, DEPTH);
  tconv(wo, wo_t, DIM_, DIM_, WQS, WQS, DEPTH);
  tconv(w1, w1_t, DIM_, 4 * DIM_, 4 * WQS, 4 * WQS, DEPTH);
  tconv(w2, w2_t, 4 * DIM_, DIM_, 4 * WQS, 4 * WQS, DEPTH);
  tconv(pk, pkv_t, N_, KLIN, (long long)N_ * KLIN, (long long)2 * KLIN * N_, DEPTH);
  tconv(pv, pkv_t + (long long)KLIN * N_, N_, KLIN, (long long)N_ * KLIN,
        (long long)2 * KLIN * N_, DEPTH);
  tconv(emb_w, emb_wt, INDIM, DIM_, 0, 0, 1);
  hipLaunchKernelGGL(cconv_k, dim3((B_ * N_ * INDIM / 8 + 255) / 256),
                     dim3(256), 0, stream, x, x_bf, B_ * N_ * INDIM / 8);

  // ---- embedding: h = bf16(x@emb_w + emb_b + pos), pos resid fp32 ----
  hipLaunchKernelGGL((gemm_bf<1, 128, 128>), dim3(DIM_ / 128, B_ * N_ / 128, 1),
                     dim3(256), 0, stream, x_bf, emb_wt, emb_b, pos, (void*)h,
                     B_ * N_, DIM_, INDIM, INDIM, INDIM, DIM_, 0LL, 0LL, 0LL,
                     0, 0LL, 2, N_);

  for (int i = 0; i < DEPTH; ++i) {
    const short* wq_i  = wq_t + i * WQS;
    const short* wkv_i = wkv_t + i * 2 * WQS;
    const short* wo_i  = wo_t + i * WQS;
    const short* w1_i  = w1_t + (long long)i * 4 * WQS;
    const short* w2_i  = w2_t + (long long)i * 4 * WQS;
    const short* pkv_i = pkv_t + (long long)i * 2 * KLIN * N_;

    // ---- attention, B_/acb chunks ----
    for (int c = 0; c < B_ / acb; ++c) {
      short* hc = h + (long long)c * acrows * DIM_;
      // fused LN1 + transpose: zc (row-major) and zcT (per-batch [DIM][N])
      hipLaunchKernelGGL(lnt_k, dim3((int)(acrows / 64)), dim3(256), 0, stream,
                         hc, ln1_s + i * DIM_, ln1_b + i * DIM_, zc, zcT);
      // qc = zc @ wq  (8-phase 256x256)
      hipLaunchKernelGGL((gemm8<1, 256, 256, 0>),
                         dim3(DIM_ / 256, (int)(acrows / 256), 1), dim3(512), 0,
                         stream, zc, wq_i, nullptr, nullptr, (void*)qc,
                         (int)acrows, DIM_, DIM_, 0LL, 0LL, 0LL, 0, 0LL);
      // zp[b] = pkv^T @ zc[b]  (2-phase 64x128, batched — proven R5 config)
      hipLaunchKernelGGL((gemm_bf<1, 64, 128>), dim3(DIM_ / 128, 512 / 64, acb),
                         dim3(256), 0, stream, pkv_i, zcT, nullptr, nullptr,
                         (void*)zp, 512, DIM_, N_, N_, N_, DIM_, 0LL,
                         (long long)DIM_ * N_, KVS, 0, 0LL, 0, 0);
      // kvp[b] = zp[b] @ [wk | wv]  (B dual by output row — proven R5 config)
      hipLaunchKernelGGL((gemm_bf<1, 64, 128>), dim3(DIM_ / 128, 512 / 64, acb),
                         dim3(256), 0, stream, zp, wkv_i, nullptr, nullptr,
                         (void*)kvp, 512, DIM_, DIM_, DIM_, DIM_, DIM_, KVS,
                         0LL, KVS, KLIN, (long long)WQS, 0, 0);
      // vt[b] = V[b]^T  (zp is dead now; conflict-free global transpose)
      hipLaunchKernelGGL(tpose_k, dim3(DIM_ / 64, KLIN / 64, acb), dim3(256), 0,
                         stream, kvp + (long long)KLIN * DIM_, vt, KLIN, DIM_,
                         KVS, (long long)DIM_ * KLIN);
      // fused attention in-place on qc (QBLK=64, 256 threads, 2 blocks/CU)
      hipLaunchKernelGGL(attn_k, dim3(N_ / 64, HEADS, acb), dim3(256), 0,
                         stream, qc, kvp, vt, scale);
      // h += qc @ wo + wo_b  (8-phase 256x256, bf16 resid/out)
      hipLaunchKernelGGL((gemm8<1, 256, 256, 2>),
                         dim3(DIM_ / 256, (int)(acrows / 256), 1), dim3(512), 0,
                         stream, qc, wo_i, wo_b + i * DIM_,
                         (const float*)hc, (void*)hc, (int)acrows, DIM_, DIM_,
                         0LL, 0LL, 0LL, 0, 0LL);
    }

    // ---- FFN, (B_*N_)/frows chunks ----
    for (int r0 = 0; r0 < B_ * N_; r0 += frows) {
      short* hr = h + (long long)r0 * DIM_;
      hipLaunchKernelGGL(ln_k, dim3(frows / 4), dim3(256), 0, stream, hr,
                         ln2_s + i * DIM_, ln2_b + i * DIM_, zln);
      // ffnmid = gelu(zln @ w1 + b1)  (merged 2-phase 128x128, 2/CU)
      hipLaunchKernelGGL((gemm8m<1, 128, 128, 3>),
                         dim3(4 * DIM_ / 128, frows / 128, 1), dim3(512), 0,
                         stream, zln, w1_i, b1 + (long long)i * 4 * DIM_,
                         nullptr, (void*)ffnmid, frows, 4 * DIM_, DIM_, 0LL,
                         0LL, 0LL, 0, 0LL);
      // h += ffnmid @ w2 + b2  (merged 2-phase 128x128, bf16 resid/out)
      hipLaunchKernelGGL((gemm8m<1, 128, 128, 2>),
                         dim3(DIM_ / 128, frows / 128, 1), dim3(512), 0,
                         stream, ffnmid, w2_i, b2 + (long long)i * DIM_,
                         (const float*)hr, (void*)hr, frows, DIM_, 4 * DIM_,
                         0LL, 0LL, 0LL, 0, 0LL);
    }
  }

  hipLaunchKernelGGL(pool1_k, dim3(16, B_), dim3(256), 0, stream, h, partial);
  hipLaunchKernelGGL(pool2_k, dim3(B_), dim3(256), 0, stream, partial, pooled);
  hipLaunchKernelGGL(fc_k, dim3(1), dim3(64), 0, stream, pooled, fc_w, fc_b,
                     out);
}